// Round 1
// baseline (5109.098 us; speedup 1.0000x reference)
//
#include <hip/hip_runtime.h>

#define HF 10   // feature width
#define ST 16   // padded row stride (floats) -> 64B-aligned rows, 1 line per gather

// ---- degrees via float atomics (exact for small counts) ----
__global__ void k_degree(const int* __restrict__ src, const int* __restrict__ dst,
                         float* __restrict__ deg_v, float* __restrict__ deg_c, int E) {
    int i = blockIdx.x * blockDim.x + threadIdx.x;
    if (i < E) {
        atomicAdd(&deg_v[src[i]], 1.0f);
        atomicAdd(&deg_c[dst[i]], 1.0f);
    }
}

// ---- deg -> rsqrt(max(deg,1)) in place ----
__global__ void k_norm(float* __restrict__ d, int n) {
    int i = blockIdx.x * blockDim.x + threadIdx.x;
    if (i < n) {
        float v = fmaxf(d[i], 1.0f);
        d[i] = 1.0f / sqrtf(v);
    }
}

// ---- h_v = (relu([c,x]@Wv + bv) * norm_v) @ W2, written to padded rows ----
__global__ void k_var_emb(const float* __restrict__ var_c, const float* __restrict__ var_x,
                          const float* __restrict__ norm_v,
                          const float* __restrict__ Wv, const float* __restrict__ bv,
                          const float* __restrict__ W2,
                          float* __restrict__ out, int NV) {
    __shared__ float sWv[2 * HF], sbv[HF], sW2[HF * HF];
    int t = threadIdx.x;
    if (t < 2 * HF) sWv[t] = Wv[t];
    if (t < HF)     sbv[t] = bv[t];
    if (t < HF * HF) sW2[t] = W2[t];
    __syncthreads();
    int i = blockIdx.x * blockDim.x + t;
    if (i >= NV) return;
    float c = var_c[i], x = var_x[i], nv = norm_v[i];
    float e[HF];
#pragma unroll
    for (int h = 0; h < HF; h++)
        e[h] = fmaxf(fmaf(c, sWv[h], fmaf(x, sWv[HF + h], sbv[h])), 0.0f) * nv;
    float* row = out + (size_t)i * ST;
#pragma unroll
    for (int j = 0; j < HF; j++) {
        float acc = 0.0f;
#pragma unroll
        for (int k = 0; k < HF; k++) acc = fmaf(e[k], sW2[k * HF + j], acc);
        row[j] = acc;
    }
}

// ---- edge scatter: agg[didx[e]] += h[gidx[e]] * A[e]; 5 threads/edge, float2 each ----
__global__ void k_edge(const int* __restrict__ gidx, const int* __restrict__ didx,
                       const float* __restrict__ A,
                       const float* __restrict__ h, float* __restrict__ agg,
                       int E) {
    int tid = blockIdx.x * blockDim.x + threadIdx.x;
    int e = tid / 5;
    if (e >= E) return;
    int q = tid - e * 5;            // 0..4 -> feature pair 2q, 2q+1
    int s = gidx[e];
    int d = didx[e];
    float a = A[e];
    const float2 m = *(const float2*)(h + (size_t)s * ST + 2 * q);
    float* o = agg + (size_t)d * ST + 2 * q;
    atomicAdd(o,     m.x * a);
    atomicAdd(o + 1, m.y * a);
}

// ---- con stage, in place: row = (relu(row*nc + b2) * nc) @ W2 ----
__global__ void k_con(float* __restrict__ buf, const float* __restrict__ norm_c,
                      const float* __restrict__ W2, const float* __restrict__ b2, int NC) {
    __shared__ float sW2[HF * HF], sb2[HF];
    int t = threadIdx.x;
    if (t < HF * HF) sW2[t] = W2[t];
    if (t < HF)      sb2[t] = b2[t];
    __syncthreads();
    int i = blockIdx.x * blockDim.x + t;
    if (i >= NC) return;
    float nc = norm_c[i];
    float* row = buf + (size_t)i * ST;
    float hc[HF];
#pragma unroll
    for (int h = 0; h < HF; h++)
        hc[h] = fmaxf(fmaf(row[h], nc, sb2[h]), 0.0f) * nc;
#pragma unroll
    for (int j = 0; j < HF; j++) {
        float acc = 0.0f;
#pragma unroll
        for (int k = 0; k < HF; k++) acc = fmaf(hc[k], sW2[k * HF + j], acc);
        row[j] = acc;
    }
}

// ---- final: h_var = relu(agg*nv + b2); 3-layer MLP; block-reduce logits (f64) ----
__global__ void k_final(const float* __restrict__ agg_v, const float* __restrict__ norm_v,
                        const float* __restrict__ b2,
                        const float* __restrict__ Wo1, const float* __restrict__ bo1,
                        const float* __restrict__ Wo2, const float* __restrict__ bo2,
                        const float* __restrict__ Wo3, const float* __restrict__ bo3,
                        double* __restrict__ acc, int NV) {
    __shared__ float sb2[HF], sW1[HF * HF], sb1[HF], sW2m[HF * HF], sb2m[HF], sW3[HF];
    __shared__ float sb3;
    __shared__ double red[256];
    int t = threadIdx.x;
    if (t < HF)      sb2[t]  = b2[t];
    if (t < HF * HF) sW1[t]  = Wo1[t];
    if (t < HF)      sb1[t]  = bo1[t];
    if (t < HF * HF) sW2m[t] = Wo2[t];
    if (t < HF)      sb2m[t] = bo2[t];
    if (t < HF)      sW3[t]  = Wo3[t];
    if (t == 0)      sb3     = bo3[0];
    __syncthreads();
    int i = blockIdx.x * blockDim.x + t;
    double local = 0.0;
    if (i < NV) {
        float nv = norm_v[i];
        const float* row = agg_v + (size_t)i * ST;
        float v[HF], h1[HF], h2[HF];
#pragma unroll
        for (int h = 0; h < HF; h++) v[h] = fmaxf(fmaf(row[h], nv, sb2[h]), 0.0f);
#pragma unroll
        for (int j = 0; j < HF; j++) {
            float a = sb1[j];
#pragma unroll
            for (int k = 0; k < HF; k++) a = fmaf(v[k], sW1[k * HF + j], a);
            h1[j] = fmaxf(a, 0.0f);
        }
#pragma unroll
        for (int j = 0; j < HF; j++) {
            float a = sb2m[j];
#pragma unroll
            for (int k = 0; k < HF; k++) a = fmaf(h1[k], sW2m[k * HF + j], a);
            h2[j] = fmaxf(a, 0.0f);
        }
        float logit = sb3;
#pragma unroll
        for (int k = 0; k < HF; k++) logit = fmaf(h2[k], sW3[k], logit);
        local = (double)logit;
    }
    red[t] = local;
    __syncthreads();
    for (int s = 128; s > 0; s >>= 1) {
        if (t < s) red[t] += red[t + s];
        __syncthreads();
    }
    if (t == 0) atomicAdd(acc, red[0]);
}

__global__ void k_out(const double* __restrict__ acc, float* __restrict__ out, int NV) {
    out[0] = (float)(acc[0] / (double)NV);
}

extern "C" void kernel_launch(void* const* d_in, const int* in_sizes, int n_in,
                              void* d_out, int out_size, void* d_ws, size_t ws_size,
                              hipStream_t stream) {
    const float* var_c = (const float*)d_in[0];
    const float* var_x = (const float*)d_in[1];
    // d_in[2] con_b unused (X_con never reaches the output path)
    const float* A   = (const float*)d_in[3];
    const int*   src = (const int*)d_in[4];
    const int*   dst = (const int*)d_in[5];
    const float* Wv  = (const float*)d_in[6];
    const float* bv  = (const float*)d_in[7];
    // d_in[8..11] Wc,bc,W1,b1 unused (conv1 output overwritten)
    const float* W2  = (const float*)d_in[12];
    const float* b2  = (const float*)d_in[13];
    const float* Wo1 = (const float*)d_in[14];
    const float* bo1 = (const float*)d_in[15];
    const float* Wo2 = (const float*)d_in[16];
    const float* bo2 = (const float*)d_in[17];
    const float* Wo3 = (const float*)d_in[18];
    const float* bo3 = (const float*)d_in[19];

    const int NV = in_sizes[0];
    const int NC = in_sizes[2];
    const int E  = in_sizes[3];

    // workspace layout
    char* ws = (char*)d_ws;
    float* bufV  = (float*)ws;                                   // NV*ST floats: h_v then agg_v
    float* bufC  = (float*)(ws + (size_t)NV * ST * 4);           // NC*ST floats: agg_c then h_c2
    float* deg_v = (float*)(ws + (size_t)(NV + NC) * ST * 4);    // NV floats (deg -> norm)
    float* deg_c = deg_v + NV;                                   // NC floats
    size_t acc_off = ((size_t)(NV + NC) * ST * 4 + (size_t)(NV + NC) * 4 + 7) & ~(size_t)7;
    double* acc  = (double*)(ws + acc_off);

    const int B = 256;
    hipMemsetAsync(deg_v, 0, (size_t)(NV + NC) * 4, stream);
    hipMemsetAsync(bufC, 0, (size_t)NC * ST * 4, stream);
    hipMemsetAsync(acc, 0, sizeof(double), stream);

    k_degree<<<(E + B - 1) / B, B, 0, stream>>>(src, dst, deg_v, deg_c, E);
    k_norm<<<(NV + NC + B - 1) / B, B, 0, stream>>>(deg_v, NV + NC);
    k_var_emb<<<(NV + B - 1) / B, B, 0, stream>>>(var_c, var_x, deg_v, Wv, bv, W2, bufV, NV);

    long long tE = (long long)E * 5;
    k_edge<<<(int)((tE + B - 1) / B), B, 0, stream>>>(src, dst, A, bufV, bufC, E);
    k_con<<<(NC + B - 1) / B, B, 0, stream>>>(bufC, deg_c, W2, b2, NC);

    hipMemsetAsync(bufV, 0, (size_t)NV * ST * 4, stream);
    k_edge<<<(int)((tE + B - 1) / B), B, 0, stream>>>(dst, src, A, bufC, bufV, E);

    k_final<<<(NV + B - 1) / B, B, 0, stream>>>(bufV, deg_v, b2, Wo1, bo1, Wo2, bo2, Wo3, bo3, acc, NV);
    k_out<<<1, 1, 0, stream>>>(acc, (float*)d_out, NV);
}

// Round 2
// 5102.145 us; speedup vs baseline: 1.0014x; 1.0014x over previous
//
#include <hip/hip_runtime.h>

#define HF 10   // feature width
#define ST 16   // padded row stride (floats) -> 64B-aligned rows, 1 line per gather
#define NBMAX 2048

// ============================================================================
// FAST PATH: counting-sort edges into dst-bins (256 con/bin) and src-bins
// (512 var/bin), then per-bin LDS aggregation -> zero global fp32 atomics.
// Key packing: D-dir (dlow<<20)|src  (needs NV<=2^20), S-dir (slow<<19)|dst
// (needs NC<=2^19).
// ============================================================================

// ---- per-chunk LDS histogram of dst>>8 and src>>9, flushed with atomics ----
__global__ void k_hist(const int* __restrict__ src, const int* __restrict__ dst,
                       unsigned* __restrict__ cntD, unsigned* __restrict__ cntS,
                       int E, int per) {
    __shared__ unsigned hD[NBMAX], hS[NBMAX];
    int t = threadIdx.x;
    for (int b = t; b < NBMAX; b += 256) { hD[b] = 0u; hS[b] = 0u; }
    __syncthreads();
    long long base = (long long)blockIdx.x * per;
    long long end = base + per; if (end > E) end = E;
    for (long long i = base + t; i < end; i += 256) {
        atomicAdd(&hD[((unsigned)dst[i]) >> 8], 1u);
        atomicAdd(&hS[((unsigned)src[i]) >> 9], 1u);
    }
    __syncthreads();
    for (int b = t; b < NBMAX; b += 256) {
        unsigned c = hD[b]; if (c) atomicAdd(&cntD[b], c);
        c = hS[b];          if (c) atomicAdd(&cntS[b], c);
    }
}

// ---- exclusive scan of the 2048-bin counts; block 0 -> D, block 1 -> S ----
__global__ void k_scan(const unsigned* __restrict__ cntD, unsigned* __restrict__ startD,
                       unsigned* __restrict__ curD,
                       const unsigned* __restrict__ cntS, unsigned* __restrict__ startS,
                       unsigned* __restrict__ curS) {
    const unsigned* cnt = blockIdx.x ? cntS : cntD;
    unsigned* start     = blockIdx.x ? startS : startD;
    unsigned* cur       = blockIdx.x ? curS : curD;
    __shared__ unsigned p[256];
    int t = threadIdx.x;
    unsigned loc[8], s = 0u;
#pragma unroll
    for (int j = 0; j < 8; j++) { loc[j] = s; s += cnt[t * 8 + j]; }
    p[t] = s;
    __syncthreads();
    unsigned own = s;
    for (int off = 1; off < 256; off <<= 1) {
        unsigned v = (t >= off) ? p[t - off] : 0u;
        __syncthreads();
        p[t] += v;
        __syncthreads();
    }
    unsigned ebase = p[t] - own;
#pragma unroll
    for (int j = 0; j < 8; j++) {
        unsigned v = ebase + loc[j];
        start[t * 8 + j] = v;
        cur[t * 8 + j] = v;
    }
    if (t == 255) start[NBMAX] = p[255];
}

// ---- partition scatter: per-chunk LDS hist -> batched cursor alloc -> fill ----
__global__ void k_scatter(const int* __restrict__ src, const int* __restrict__ dst,
                          const float* __restrict__ A,
                          unsigned* __restrict__ curD, unsigned* __restrict__ curS,
                          unsigned* __restrict__ keysD, float* __restrict__ AD,
                          unsigned* __restrict__ keysS, float* __restrict__ AS,
                          int E, int per) {
    __shared__ unsigned hD[NBMAX], hS[NBMAX], bD[NBMAX], bS[NBMAX];
    int t = threadIdx.x;
    for (int b = t; b < NBMAX; b += 256) { hD[b] = 0u; hS[b] = 0u; }
    __syncthreads();
    long long base = (long long)blockIdx.x * per;
    long long end = base + per; if (end > E) end = E;
    for (long long i = base + t; i < end; i += 256) {
        atomicAdd(&hD[((unsigned)dst[i]) >> 8], 1u);
        atomicAdd(&hS[((unsigned)src[i]) >> 9], 1u);
    }
    __syncthreads();
    for (int b = t; b < NBMAX; b += 256) {
        unsigned c = hD[b]; bD[b] = c ? atomicAdd(&curD[b], c) : 0u;
        c = hS[b];          bS[b] = c ? atomicAdd(&curS[b], c) : 0u;
    }
    __syncthreads();
    for (long long i = base + t; i < end; i += 256) {
        unsigned s = (unsigned)src[i], d = (unsigned)dst[i];
        float a = A[i];
        unsigned pD = atomicAdd(&bD[d >> 8], 1u);
        keysD[pD] = ((d & 255u) << 20) | s;
        AD[pD] = a;
        unsigned pS = atomicAdd(&bS[s >> 9], 1u);
        keysS[pS] = ((s & 511u) << 19) | d;
        AS[pS] = a;
    }
}

// ---- norm_v from sorted S keys: LDS counts, dense write, no global atomics ----
__global__ void k_degv(const unsigned* __restrict__ keysS, const unsigned* __restrict__ startS,
                       float* __restrict__ norm_v, int NV) {
    __shared__ float cnt[512];
    int t = threadIdx.x, b = blockIdx.x;
    cnt[t] = 0.0f; cnt[t + 256] = 0.0f;
    __syncthreads();
    unsigned s0 = startS[b], s1 = startS[b + 1];
    for (unsigned i = s0 + t; i < s1; i += 256)
        atomicAdd(&cnt[keysS[i] >> 19], 1.0f);
    __syncthreads();
    int v0 = b * 512 + t;
    if (v0 < NV) norm_v[v0] = rsqrtf(fmaxf(cnt[t], 1.0f));
    int v1 = v0 + 256;
    if (v1 < NV) norm_v[v1] = rsqrtf(fmaxf(cnt[t + 256], 1.0f));
}

// ---- h_v = (relu([c,x]@Wv + bv) * norm_v) @ W2, padded rows ----
__global__ void k_var_emb(const float* __restrict__ var_c, const float* __restrict__ var_x,
                          const float* __restrict__ norm_v,
                          const float* __restrict__ Wv, const float* __restrict__ bv,
                          const float* __restrict__ W2,
                          float* __restrict__ out, int NV) {
    __shared__ float sWv[2 * HF], sbv[HF], sW2[HF * HF];
    int t = threadIdx.x;
    if (t < 2 * HF) sWv[t] = Wv[t];
    if (t < HF)     sbv[t] = bv[t];
    if (t < HF * HF) sW2[t] = W2[t];
    __syncthreads();
    int i = blockIdx.x * blockDim.x + t;
    if (i >= NV) return;
    float c = var_c[i], x = var_x[i], nv = norm_v[i];
    float e[HF];
#pragma unroll
    for (int h = 0; h < HF; h++)
        e[h] = fmaxf(fmaf(c, sWv[h], fmaf(x, sWv[HF + h], sbv[h])), 0.0f) * nv;
    float* row = out + (size_t)i * ST;
    float o[HF];
#pragma unroll
    for (int j = 0; j < HF; j++) {
        float acc = 0.0f;
#pragma unroll
        for (int k = 0; k < HF; k++) acc = fmaf(e[k], sW2[k * HF + j], acc);
        o[j] = acc;
    }
    *(float4*)row       = make_float4(o[0], o[1], o[2], o[3]);
    *(float4*)(row + 4) = make_float4(o[4], o[5], o[6], o[7]);
    *(float2*)(row + 8) = make_float2(o[8], o[9]);
}

// ---- v2c aggregate: one wg per con-bin; LDS accumulate; fused con transform ----
__global__ void k_aggD(const unsigned* __restrict__ keysD, const float* __restrict__ AD,
                       const unsigned* __restrict__ startD,
                       const float* __restrict__ hv,
                       const float* __restrict__ W2, const float* __restrict__ b2,
                       float* __restrict__ hc2, int NC) {
    __shared__ float acc[256 * HF];
    __shared__ float cnt[256];
    __shared__ float sW2[HF * HF], sb2[HF];
    int t = threadIdx.x, b = blockIdx.x;
    for (int i = t; i < 256 * HF; i += 256) acc[i] = 0.0f;
    cnt[t] = 0.0f;
    if (t < HF * HF) sW2[t] = W2[t];
    if (t < HF)      sb2[t] = b2[t];
    __syncthreads();
    unsigned s0 = startD[b], s1 = startD[b + 1];
    for (unsigned i = s0 + t; i < s1; i += 256) {
        unsigned k = keysD[i];
        float a = AD[i];
        unsigned s = k & 0xFFFFFu, dl = k >> 20;
        const float* row = hv + (size_t)s * ST;
        float4 v0 = *(const float4*)row;
        float4 v1 = *(const float4*)(row + 4);
        float2 v2 = *(const float2*)(row + 8);
        float* ac = acc + dl * HF;
        atomicAdd(ac + 0, a * v0.x); atomicAdd(ac + 1, a * v0.y);
        atomicAdd(ac + 2, a * v0.z); atomicAdd(ac + 3, a * v0.w);
        atomicAdd(ac + 4, a * v1.x); atomicAdd(ac + 5, a * v1.y);
        atomicAdd(ac + 6, a * v1.z); atomicAdd(ac + 7, a * v1.w);
        atomicAdd(ac + 8, a * v2.x); atomicAdd(ac + 9, a * v2.y);
        atomicAdd(&cnt[dl], 1.0f);
    }
    __syncthreads();
    int dstid = b * 256 + t;
    if (dstid < NC) {
        float nc = rsqrtf(fmaxf(cnt[t], 1.0f));
        float y[HF];
#pragma unroll
        for (int h = 0; h < HF; h++)
            y[h] = fmaxf(fmaf(acc[t * HF + h], nc, sb2[h]), 0.0f) * nc;
        float o[HF];
#pragma unroll
        for (int j = 0; j < HF; j++) {
            float a = 0.0f;
#pragma unroll
            for (int k = 0; k < HF; k++) a = fmaf(y[k], sW2[k * HF + j], a);
            o[j] = a;
        }
        float* orow = hc2 + (size_t)dstid * ST;
        *(float4*)orow       = make_float4(o[0], o[1], o[2], o[3]);
        *(float4*)(orow + 4) = make_float4(o[4], o[5], o[6], o[7]);
        *(float2*)(orow + 8) = make_float2(o[8], o[9]);
    }
}

// ---- c2v aggregate: one wg per var-bin; LDS accumulate; fused MLP + mean ----
__global__ void k_aggS(const unsigned* __restrict__ keysS, const float* __restrict__ AS,
                       const unsigned* __restrict__ startS,
                       const float* __restrict__ hc2, const float* __restrict__ norm_v,
                       const float* __restrict__ b2,
                       const float* __restrict__ Wo1, const float* __restrict__ bo1,
                       const float* __restrict__ Wo2, const float* __restrict__ bo2,
                       const float* __restrict__ Wo3, const float* __restrict__ bo3,
                       double* __restrict__ gacc, int NV) {
    __shared__ float acc[512 * HF];
    __shared__ float sb2[HF], sW1[HF * HF], sb1[HF], sW2m[HF * HF], sb2m[HF], sW3[HF];
    __shared__ float sb3;
    __shared__ double red[256];
    int t = threadIdx.x, b = blockIdx.x;
    for (int i = t; i < 512 * HF; i += 256) acc[i] = 0.0f;
    if (t < HF)      sb2[t]  = b2[t];
    if (t < HF * HF) sW1[t]  = Wo1[t];
    if (t < HF)      sb1[t]  = bo1[t];
    if (t < HF * HF) sW2m[t] = Wo2[t];
    if (t < HF)      sb2m[t] = bo2[t];
    if (t < HF)      sW3[t]  = Wo3[t];
    if (t == 0)      sb3     = bo3[0];
    __syncthreads();
    unsigned s0 = startS[b], s1 = startS[b + 1];
    for (unsigned i = s0 + t; i < s1; i += 256) {
        unsigned k = keysS[i];
        float a = AS[i];
        unsigned d = k & 0x7FFFFu, sl = k >> 19;
        const float* row = hc2 + (size_t)d * ST;
        float4 v0 = *(const float4*)row;
        float4 v1 = *(const float4*)(row + 4);
        float2 v2 = *(const float2*)(row + 8);
        float* ac = acc + sl * HF;
        atomicAdd(ac + 0, a * v0.x); atomicAdd(ac + 1, a * v0.y);
        atomicAdd(ac + 2, a * v0.z); atomicAdd(ac + 3, a * v0.w);
        atomicAdd(ac + 4, a * v1.x); atomicAdd(ac + 5, a * v1.y);
        atomicAdd(ac + 6, a * v1.z); atomicAdd(ac + 7, a * v1.w);
        atomicAdd(ac + 8, a * v2.x); atomicAdd(ac + 9, a * v2.y);
    }
    __syncthreads();
    double local = 0.0;
#pragma unroll
    for (int rr = 0; rr < 2; rr++) {
        int r = t + rr * 256;
        int v = b * 512 + r;
        if (v < NV) {
            float nv = norm_v[v];
            float x[HF], h1[HF], h2[HF];
#pragma unroll
            for (int h = 0; h < HF; h++)
                x[h] = fmaxf(fmaf(acc[r * HF + h], nv, sb2[h]), 0.0f);
#pragma unroll
            for (int j = 0; j < HF; j++) {
                float a = sb1[j];
#pragma unroll
                for (int k = 0; k < HF; k++) a = fmaf(x[k], sW1[k * HF + j], a);
                h1[j] = fmaxf(a, 0.0f);
            }
#pragma unroll
            for (int j = 0; j < HF; j++) {
                float a = sb2m[j];
#pragma unroll
                for (int k = 0; k < HF; k++) a = fmaf(h1[k], sW2m[k * HF + j], a);
                h2[j] = fmaxf(a, 0.0f);
            }
            float logit = sb3;
#pragma unroll
            for (int k = 0; k < HF; k++) logit = fmaf(h2[k], sW3[k], logit);
            local += (double)logit;
        }
    }
    red[t] = local;
    __syncthreads();
    for (int s = 128; s > 0; s >>= 1) {
        if (t < s) red[t] += red[t + s];
        __syncthreads();
    }
    if (t == 0) atomicAdd(gacc, red[0]);
}

__global__ void k_out(const double* __restrict__ acc, float* __restrict__ out, int NV) {
    out[0] = (float)(acc[0] / (double)NV);
}

// ============================================================================
// FALLBACK PATH (round-1): global-atomic scatter. Used if ws too small.
// ============================================================================

__global__ void k_degree(const int* __restrict__ src, const int* __restrict__ dst,
                         float* __restrict__ deg_v, float* __restrict__ deg_c, int E) {
    int i = blockIdx.x * blockDim.x + threadIdx.x;
    if (i < E) {
        atomicAdd(&deg_v[src[i]], 1.0f);
        atomicAdd(&deg_c[dst[i]], 1.0f);
    }
}

__global__ void k_norm(float* __restrict__ d, int n) {
    int i = blockIdx.x * blockDim.x + threadIdx.x;
    if (i < n) d[i] = 1.0f / sqrtf(fmaxf(d[i], 1.0f));
}

__global__ void k_edge(const int* __restrict__ gidx, const int* __restrict__ didx,
                       const float* __restrict__ A,
                       const float* __restrict__ h, float* __restrict__ agg, int E) {
    int tid = blockIdx.x * blockDim.x + threadIdx.x;
    int e = tid / 5;
    if (e >= E) return;
    int q = tid - e * 5;
    int s = gidx[e], d = didx[e];
    float a = A[e];
    const float2 m = *(const float2*)(h + (size_t)s * ST + 2 * q);
    float* o = agg + (size_t)d * ST + 2 * q;
    atomicAdd(o,     m.x * a);
    atomicAdd(o + 1, m.y * a);
}

__global__ void k_con(float* __restrict__ buf, const float* __restrict__ norm_c,
                      const float* __restrict__ W2, const float* __restrict__ b2, int NC) {
    __shared__ float sW2[HF * HF], sb2[HF];
    int t = threadIdx.x;
    if (t < HF * HF) sW2[t] = W2[t];
    if (t < HF)      sb2[t] = b2[t];
    __syncthreads();
    int i = blockIdx.x * blockDim.x + t;
    if (i >= NC) return;
    float nc = norm_c[i];
    float* row = buf + (size_t)i * ST;
    float hc[HF];
#pragma unroll
    for (int h = 0; h < HF; h++)
        hc[h] = fmaxf(fmaf(row[h], nc, sb2[h]), 0.0f) * nc;
#pragma unroll
    for (int j = 0; j < HF; j++) {
        float acc = 0.0f;
#pragma unroll
        for (int k = 0; k < HF; k++) acc = fmaf(hc[k], sW2[k * HF + j], acc);
        row[j] = acc;
    }
}

__global__ void k_final(const float* __restrict__ agg_v, const float* __restrict__ norm_v,
                        const float* __restrict__ b2,
                        const float* __restrict__ Wo1, const float* __restrict__ bo1,
                        const float* __restrict__ Wo2, const float* __restrict__ bo2,
                        const float* __restrict__ Wo3, const float* __restrict__ bo3,
                        double* __restrict__ acc, int NV) {
    __shared__ float sb2[HF], sW1[HF * HF], sb1[HF], sW2m[HF * HF], sb2m[HF], sW3[HF];
    __shared__ float sb3;
    __shared__ double red[256];
    int t = threadIdx.x;
    if (t < HF)      sb2[t]  = b2[t];
    if (t < HF * HF) sW1[t]  = Wo1[t];
    if (t < HF)      sb1[t]  = bo1[t];
    if (t < HF * HF) sW2m[t] = Wo2[t];
    if (t < HF)      sb2m[t] = bo2[t];
    if (t < HF)      sW3[t]  = Wo3[t];
    if (t == 0)      sb3     = bo3[0];
    __syncthreads();
    int i = blockIdx.x * blockDim.x + t;
    double local = 0.0;
    if (i < NV) {
        float nv = norm_v[i];
        const float* row = agg_v + (size_t)i * ST;
        float v[HF], h1[HF], h2[HF];
#pragma unroll
        for (int h = 0; h < HF; h++) v[h] = fmaxf(fmaf(row[h], nv, sb2[h]), 0.0f);
#pragma unroll
        for (int j = 0; j < HF; j++) {
            float a = sb1[j];
#pragma unroll
            for (int k = 0; k < HF; k++) a = fmaf(v[k], sW1[k * HF + j], a);
            h1[j] = fmaxf(a, 0.0f);
        }
#pragma unroll
        for (int j = 0; j < HF; j++) {
            float a = sb2m[j];
#pragma unroll
            for (int k = 0; k < HF; k++) a = fmaf(h1[k], sW2m[k * HF + j], a);
            h2[j] = fmaxf(a, 0.0f);
        }
        float logit = sb3;
#pragma unroll
        for (int k = 0; k < HF; k++) logit = fmaf(h2[k], sW3[k], logit);
        local = (double)logit;
    }
    red[t] = local;
    __syncthreads();
    for (int s = 128; s > 0; s >>= 1) {
        if (t < s) red[t] += red[t + s];
        __syncthreads();
    }
    if (t == 0) atomicAdd(acc, red[0]);
}

// ============================================================================

extern "C" void kernel_launch(void* const* d_in, const int* in_sizes, int n_in,
                              void* d_out, int out_size, void* d_ws, size_t ws_size,
                              hipStream_t stream) {
    const float* var_c = (const float*)d_in[0];
    const float* var_x = (const float*)d_in[1];
    const float* A   = (const float*)d_in[3];
    const int*   src = (const int*)d_in[4];
    const int*   dst = (const int*)d_in[5];
    const float* Wv  = (const float*)d_in[6];
    const float* bv  = (const float*)d_in[7];
    const float* W2  = (const float*)d_in[12];
    const float* b2  = (const float*)d_in[13];
    const float* Wo1 = (const float*)d_in[14];
    const float* bo1 = (const float*)d_in[15];
    const float* Wo2 = (const float*)d_in[16];
    const float* bo2 = (const float*)d_in[17];
    const float* Wo3 = (const float*)d_in[18];
    const float* bo3 = (const float*)d_in[19];

    const int NV = in_sizes[0];
    const int NC = in_sizes[2];
    const int E  = in_sizes[3];
    const int B  = 256;

    // fast-path workspace layout
    char* ws = (char*)d_ws;
    size_t off = 0;
    auto alloc = [&](size_t bytes) -> void* {
        void* p = ws + off;
        off = (off + bytes + 255) & ~(size_t)255;
        return p;
    };
    float*    bufV   = (float*)alloc((size_t)NV * ST * 4);
    float*    bufC   = (float*)alloc((size_t)NC * ST * 4);
    unsigned* keysD  = (unsigned*)alloc((size_t)E * 4);
    float*    AD     = (float*)alloc((size_t)E * 4);
    unsigned* keysS  = (unsigned*)alloc((size_t)E * 4);
    float*    AS     = (float*)alloc((size_t)E * 4);
    float*    norm_v = (float*)alloc((size_t)NV * 4);
    unsigned* cntD   = (unsigned*)alloc(NBMAX * 4);
    unsigned* cntS   = (unsigned*)alloc(NBMAX * 4);
    unsigned* startD = (unsigned*)alloc((NBMAX + 1) * 4);
    unsigned* curD   = (unsigned*)alloc(NBMAX * 4);
    unsigned* startS = (unsigned*)alloc((NBMAX + 1) * 4);
    unsigned* curS   = (unsigned*)alloc(NBMAX * 4);
    double*   gacc   = (double*)alloc(8);
    size_t need = off;

    bool fast = (need <= ws_size) && (NV <= (1 << 20)) && (NC <= (1 << 19));

    if (fast) {
        hipMemsetAsync(cntD, 0, NBMAX * 4, stream);
        hipMemsetAsync(cntS, 0, NBMAX * 4, stream);
        hipMemsetAsync(gacc, 0, 8, stream);

        const int GP  = 512;                 // partition grid
        const int per = (E + GP - 1) / GP;
        const int NB_D = (NC + 255) >> 8;
        const int NB_S = (NV + 511) >> 9;

        k_hist<<<GP, B, 0, stream>>>(src, dst, cntD, cntS, E, per);
        k_scan<<<2, B, 0, stream>>>(cntD, startD, curD, cntS, startS, curS);
        k_scatter<<<GP, B, 0, stream>>>(src, dst, A, curD, curS,
                                        keysD, AD, keysS, AS, E, per);
        k_degv<<<NB_S, B, 0, stream>>>(keysS, startS, norm_v, NV);
        k_var_emb<<<(NV + B - 1) / B, B, 0, stream>>>(var_c, var_x, norm_v,
                                                      Wv, bv, W2, bufV, NV);
        k_aggD<<<NB_D, B, 0, stream>>>(keysD, AD, startD, bufV, W2, b2, bufC, NC);
        k_aggS<<<NB_S, B, 0, stream>>>(keysS, AS, startS, bufC, norm_v, b2,
                                       Wo1, bo1, Wo2, bo2, Wo3, bo3, gacc, NV);
        k_out<<<1, 1, 0, stream>>>(gacc, (float*)d_out, NV);
    } else {
        // round-1 layout/path
        float* fbufV = (float*)ws;
        float* fbufC = (float*)(ws + (size_t)NV * ST * 4);
        float* deg_v = (float*)(ws + (size_t)(NV + NC) * ST * 4);
        float* deg_c = deg_v + NV;
        size_t acc_off = ((size_t)(NV + NC) * ST * 4 + (size_t)(NV + NC) * 4 + 7) & ~(size_t)7;
        double* acc = (double*)(ws + acc_off);

        hipMemsetAsync(deg_v, 0, (size_t)(NV + NC) * 4, stream);
        hipMemsetAsync(fbufC, 0, (size_t)NC * ST * 4, stream);
        hipMemsetAsync(acc, 0, sizeof(double), stream);

        k_degree<<<(E + B - 1) / B, B, 0, stream>>>(src, dst, deg_v, deg_c, E);
        k_norm<<<(NV + NC + B - 1) / B, B, 0, stream>>>(deg_v, NV + NC);
        k_var_emb<<<(NV + B - 1) / B, B, 0, stream>>>(var_c, var_x, deg_v, Wv, bv, W2, fbufV, NV);

        long long tE = (long long)E * 5;
        k_edge<<<(int)((tE + B - 1) / B), B, 0, stream>>>(src, dst, A, fbufV, fbufC, E);
        k_con<<<(NC + B - 1) / B, B, 0, stream>>>(fbufC, deg_c, W2, b2, NC);

        hipMemsetAsync(fbufV, 0, (size_t)NV * ST * 4, stream);
        k_edge<<<(int)((tE + B - 1) / B), B, 0, stream>>>(dst, src, A, fbufC, fbufV, E);

        k_final<<<(NV + B - 1) / B, B, 0, stream>>>(fbufV, deg_v, b2, Wo1, bo1, Wo2, bo2, Wo3, bo3, acc, NV);
        k_out<<<1, 1, 0, stream>>>(acc, (float*)d_out, NV);
    }
}

// Round 3
// 3221.228 us; speedup vs baseline: 1.5861x; 1.5839x over previous
//
#include <hip/hip_runtime.h>

#define HF 10      // feature width
#define ST 16      // fallback-path row stride
#define SLC 128    // slices (scatter WGs) per chunk
#define NBINS 2048 // bins per direction (512 nodes/bin)

// ============================================================================
// FAST PATH: memory-adaptive chunked counting-sort + LDS-binned aggregation.
// Zero global fp32 atomics. ebuf (one chunk of 8-B key+A payloads) is reused
// across phases: S-count (degrees) -> D-agg (v2c) -> S-agg (c2v).
// Keys: D = (dlow9<<20)|src20, S = (slow9<<19)|dst19.
// W2 deferred through the linear segment-sum; var embedding computed on the
// fly in the aggregator from scalar gathers.
// ============================================================================

// ---- per-(chunk,slice) histograms of src>>9 and dst>>9 ----
__global__ void k_hist(const int* __restrict__ src, const int* __restrict__ dst,
                       unsigned* __restrict__ hS, unsigned* __restrict__ hD,
                       int E, int EcMax, int c, int per) {
    __shared__ unsigned lS[NBINS], lD[NBINS];
    int t = threadIdx.x, sl = blockIdx.x;
    for (int b = t; b < NBINS; b += 512) { lS[b] = 0u; lD[b] = 0u; }
    __syncthreads();
    long long cs = (long long)c * EcMax;
    long long ce = cs + EcMax; if (ce > E) ce = E;
    long long s0 = cs + (long long)sl * per;
    long long s1 = s0 + per; if (s1 > ce) s1 = ce;
    for (long long i = s0 + t; i < s1; i += 512) {
        atomicAdd(&lS[((unsigned)src[i]) >> 9], 1u);
        atomicAdd(&lD[((unsigned)dst[i]) >> 9], 1u);
    }
    __syncthreads();
    size_t base = ((size_t)c * SLC + sl) * NBINS;
    for (int b = t; b < NBINS; b += 512) { hS[base + b] = lS[b]; hD[base + b] = lD[b]; }
}

// ---- scan: per-bin totals -> block prefix -> per-slice exclusive cursors.
// offs written IN PLACE over h (each cell read once then overwritten). ----
__global__ __launch_bounds__(1024) void k_scan(unsigned* __restrict__ hS, unsigned* __restrict__ hD,
                       unsigned* __restrict__ startS, unsigned* __restrict__ startD) {
    int c = blockIdx.x;
    unsigned* h     = blockIdx.y ? hD : hS;
    unsigned* start = blockIdx.y ? startD : startS;
    h += (size_t)c * SLC * NBINS;
    start += (size_t)c * (NBINS + 1);
    __shared__ unsigned p[1024];
    int t = threadIdx.x;
    int b0 = 2 * t;
    unsigned tot0 = 0u, tot1 = 0u;
    for (int sl = 0; sl < SLC; sl++) {
        uint2 v = *(const uint2*)(h + (size_t)sl * NBINS + b0);
        tot0 += v.x; tot1 += v.y;
    }
    unsigned own = tot0 + tot1;
    p[t] = own;
    __syncthreads();
    for (int off = 1; off < 1024; off <<= 1) {
        unsigned v = (t >= off) ? p[t - off] : 0u;
        __syncthreads();
        p[t] += v;
        __syncthreads();
    }
    unsigned e0 = p[t] - own;        // exclusive base for bin b0
    unsigned e1 = e0 + tot0;         // for bin b0+1
    start[b0] = e0; start[b0 + 1] = e1;
    if (t == 1023) start[NBINS] = p[1023];
    unsigned s0 = e0, s1 = e1;
    for (int sl = 0; sl < SLC; sl++) {
        unsigned* cell = h + (size_t)sl * NBINS + b0;
        uint2 v = *(const uint2*)cell;
        *(uint2*)cell = make_uint2(s0, s1);
        s0 += v.x; s1 += v.y;
    }
}

// ---- phase-1 scatter: src low-bits only (2 B) for degree counting ----
__global__ void k_scatU(const int* __restrict__ src, const unsigned* __restrict__ offsS,
                        unsigned short* __restrict__ sbuf, int E, int EcMax, int c, int per) {
    __shared__ unsigned cur[NBINS];
    int t = threadIdx.x, sl = blockIdx.x;
    const unsigned* o = offsS + ((size_t)c * SLC + sl) * NBINS;
    for (int b = t; b < NBINS; b += 512) cur[b] = o[b];
    __syncthreads();
    long long cs = (long long)c * EcMax;
    long long ce = cs + EcMax; if (ce > E) ce = E;
    long long s0 = cs + (long long)sl * per;
    long long s1 = s0 + per; if (s1 > ce) s1 = ce;
    for (long long i = s0 + t; i < s1; i += 512) {
        unsigned s = (unsigned)src[i];
        unsigned pos = atomicAdd(&cur[s >> 9], 1u);
        sbuf[pos] = (unsigned short)(s & 511u);
    }
}

// ---- phase-1 consumer: per-bin LDS count -> deg_v (WG-owned, plain RMW) ----
__global__ void k_cntS(const unsigned short* __restrict__ sbuf, const unsigned* __restrict__ startS,
                       float* __restrict__ deg_v, int c, int NV) {
    __shared__ unsigned cnt[512];
    int t = threadIdx.x, b = blockIdx.x;
    cnt[t] = 0u; cnt[t + 256] = 0u;
    __syncthreads();
    const unsigned* st = startS + (size_t)c * (NBINS + 1);
    unsigned i0 = st[b], i1 = st[b + 1];
    for (unsigned i = i0 + t; i < i1; i += 256)
        atomicAdd(&cnt[sbuf[i]], 1u);
    __syncthreads();
    int v = b * 512 + t;
    if (v < NV) deg_v[v] += (float)cnt[t];
    v += 256;
    if (v < NV) deg_v[v] += (float)cnt[t + 256];
}

__global__ void k_normv(float* __restrict__ d, int n) {
    int i = blockIdx.x * blockDim.x + threadIdx.x;
    if (i < n) d[i] = rsqrtf(fmaxf(d[i], 1.0f));
}

// ---- full scatter, D direction: key=(dlow<<20)|src, payload A ----
__global__ void k_scatD(const int* __restrict__ src, const int* __restrict__ dst,
                        const float* __restrict__ A, const unsigned* __restrict__ offsD,
                        uint2* __restrict__ ebuf, int E, int EcMax, int c, int per) {
    __shared__ unsigned cur[NBINS];
    int t = threadIdx.x, sl = blockIdx.x;
    const unsigned* o = offsD + ((size_t)c * SLC + sl) * NBINS;
    for (int b = t; b < NBINS; b += 512) cur[b] = o[b];
    __syncthreads();
    long long cs = (long long)c * EcMax;
    long long ce = cs + EcMax; if (ce > E) ce = E;
    long long s0 = cs + (long long)sl * per;
    long long s1 = s0 + per; if (s1 > ce) s1 = ce;
    for (long long i = s0 + t; i < s1; i += 512) {
        unsigned s = (unsigned)src[i], d = (unsigned)dst[i];
        float a = A[i];
        unsigned pos = atomicAdd(&cur[d >> 9], 1u);
        ebuf[pos] = make_uint2(((d & 511u) << 20) | s, __float_as_uint(a));
    }
}

// ---- full scatter, S direction: key=(slow<<19)|dst, payload A ----
__global__ void k_scatS(const int* __restrict__ src, const int* __restrict__ dst,
                        const float* __restrict__ A, const unsigned* __restrict__ offsS,
                        uint2* __restrict__ ebuf, int E, int EcMax, int c, int per) {
    __shared__ unsigned cur[NBINS];
    int t = threadIdx.x, sl = blockIdx.x;
    const unsigned* o = offsS + ((size_t)c * SLC + sl) * NBINS;
    for (int b = t; b < NBINS; b += 512) cur[b] = o[b];
    __syncthreads();
    long long cs = (long long)c * EcMax;
    long long ce = cs + EcMax; if (ce > E) ce = E;
    long long s0 = cs + (long long)sl * per;
    long long s1 = s0 + per; if (s1 > ce) s1 = ce;
    for (long long i = s0 + t; i < s1; i += 512) {
        unsigned s = (unsigned)src[i], d = (unsigned)dst[i];
        float a = A[i];
        unsigned pos = atomicAdd(&cur[s >> 9], 1u);
        ebuf[pos] = make_uint2(((s & 511u) << 19) | d, __float_as_uint(a));
    }
}

// ---- v2c aggregate: on-the-fly var embedding, LDS bin accumulate, RMW flush ----
__global__ void k_aggD(const uint2* __restrict__ ebuf, const unsigned* __restrict__ startD,
                       const float* __restrict__ var_c, const float* __restrict__ var_x,
                       const float* __restrict__ nrm,
                       const float* __restrict__ Wv, const float* __restrict__ bv,
                       float* __restrict__ bufC, float* __restrict__ deg_c, int c, int NC) {
    __shared__ float acc[512 * HF];
    __shared__ unsigned cnt[512];
    int t = threadIdx.x, b = blockIdx.x;
    for (int i = t; i < 512 * HF; i += 256) acc[i] = 0.0f;
    cnt[t] = 0u; cnt[t + 256] = 0u;
    float wv0[HF], wv1[HF], bvv[HF];
#pragma unroll
    for (int h = 0; h < HF; h++) { wv0[h] = Wv[h]; wv1[h] = Wv[HF + h]; bvv[h] = bv[h]; }
    __syncthreads();
    const unsigned* st = startD + (size_t)c * (NBINS + 1);
    unsigned i0 = st[b], i1 = st[b + 1];
    for (unsigned i = i0 + t; i < i1; i += 256) {
        uint2 kv = ebuf[i];
        float a = __uint_as_float(kv.y);
        unsigned s = kv.x & 0xFFFFFu, dl = kv.x >> 20;
        float cc = var_c[s], xx = var_x[s];
        float anv = a * nrm[s];
        float* ac = acc + dl * HF;
#pragma unroll
        for (int h = 0; h < HF; h++) {
            float e = fmaxf(fmaf(cc, wv0[h], fmaf(xx, wv1[h], bvv[h])), 0.0f);
            atomicAdd(ac + h, anv * e);
        }
        atomicAdd(&cnt[dl], 1u);
    }
    __syncthreads();
#pragma unroll
    for (int rr = 0; rr < 2; rr++) {
        int r = t + rr * 256;
        int gid = b * 512 + r;
        if (gid < NC) {
            float* row = bufC + (size_t)gid * HF;
#pragma unroll
            for (int h = 0; h < HF; h++) row[h] += acc[r * HF + h];
            deg_c[gid] += (float)cnt[r];
        }
    }
}

// ---- con transform in place: y = relu((row@W2)*nc + b2)*nc ----
__global__ void k_conT(float* __restrict__ bufC, const float* __restrict__ deg_c,
                       const float* __restrict__ W2, const float* __restrict__ b2, int NC) {
    __shared__ float sW[HF * HF], sb[HF];
    int t = threadIdx.x;
    if (t < HF * HF) sW[t] = W2[t];
    if (t < HF)      sb[t] = b2[t];
    __syncthreads();
    int i = blockIdx.x * 256 + t;
    if (i >= NC) return;
    float nc = rsqrtf(fmaxf(deg_c[i], 1.0f));
    float* row = bufC + (size_t)i * HF;
    float x[HF];
#pragma unroll
    for (int h = 0; h < HF; h++) x[h] = row[h];
#pragma unroll
    for (int j = 0; j < HF; j++) {
        float a = 0.0f;
#pragma unroll
        for (int k = 0; k < HF; k++) a = fmaf(x[k], sW[k * HF + j], a);
        row[j] = fmaxf(fmaf(a, nc, sb[j]), 0.0f) * nc;
    }
}

// ---- c2v aggregate: gather y rows, LDS bin accumulate, RMW flush ----
__global__ void k_aggS(const uint2* __restrict__ ebuf, const unsigned* __restrict__ startS,
                       const float* __restrict__ bufC, float* __restrict__ bufV, int c, int NV) {
    __shared__ float acc[512 * HF];
    int t = threadIdx.x, b = blockIdx.x;
    for (int i = t; i < 512 * HF; i += 256) acc[i] = 0.0f;
    __syncthreads();
    const unsigned* st = startS + (size_t)c * (NBINS + 1);
    unsigned i0 = st[b], i1 = st[b + 1];
    for (unsigned i = i0 + t; i < i1; i += 256) {
        uint2 kv = ebuf[i];
        float a = __uint_as_float(kv.y);
        unsigned d = kv.x & 0x7FFFFu, sl = kv.x >> 19;
        const float* yr = bufC + (size_t)d * HF;
        float2 y0 = *(const float2*)yr;
        float2 y1 = *(const float2*)(yr + 2);
        float2 y2 = *(const float2*)(yr + 4);
        float2 y3 = *(const float2*)(yr + 6);
        float2 y4 = *(const float2*)(yr + 8);
        float* ac = acc + sl * HF;
        atomicAdd(ac + 0, a * y0.x); atomicAdd(ac + 1, a * y0.y);
        atomicAdd(ac + 2, a * y1.x); atomicAdd(ac + 3, a * y1.y);
        atomicAdd(ac + 4, a * y2.x); atomicAdd(ac + 5, a * y2.y);
        atomicAdd(ac + 6, a * y3.x); atomicAdd(ac + 7, a * y3.y);
        atomicAdd(ac + 8, a * y4.x); atomicAdd(ac + 9, a * y4.y);
    }
    __syncthreads();
#pragma unroll
    for (int rr = 0; rr < 2; rr++) {
        int r = t + rr * 256;
        int gid = b * 512 + r;
        if (gid < NV) {
            float* row = bufV + (size_t)gid * HF;
#pragma unroll
            for (int h = 0; h < HF; h++) row[h] += acc[r * HF + h];
        }
    }
}

// ---- final: h_var = relu((row@W2)*nv + b2) -> MLP -> mean (double) ----
__global__ void k_final2(const float* __restrict__ bufV, const float* __restrict__ nrm,
                         const float* __restrict__ W2, const float* __restrict__ b2,
                         const float* __restrict__ Wo1, const float* __restrict__ bo1,
                         const float* __restrict__ Wo2, const float* __restrict__ bo2,
                         const float* __restrict__ Wo3, const float* __restrict__ bo3,
                         double* __restrict__ gacc, int NV) {
    __shared__ float sW2[HF * HF], sb2[HF], sW1[HF * HF], sb1[HF], sWm[HF * HF], sbm[HF], sW3[HF];
    __shared__ float sb3;
    __shared__ double red[256];
    int t = threadIdx.x;
    if (t < HF * HF) sW2[t] = W2[t];
    if (t < HF)      sb2[t] = b2[t];
    if (t < HF * HF) sW1[t] = Wo1[t];
    if (t < HF)      sb1[t] = bo1[t];
    if (t < HF * HF) sWm[t] = Wo2[t];
    if (t < HF)      sbm[t] = bo2[t];
    if (t < HF)      sW3[t] = Wo3[t];
    if (t == 0)      sb3    = bo3[0];
    __syncthreads();
    int i = blockIdx.x * 256 + t;
    double local = 0.0;
    if (i < NV) {
        float nv = nrm[i];
        const float* row = bufV + (size_t)i * HF;
        float x[HF], v[HF], h1[HF], h2[HF];
#pragma unroll
        for (int h = 0; h < HF; h++) x[h] = row[h];
#pragma unroll
        for (int j = 0; j < HF; j++) {
            float a = 0.0f;
#pragma unroll
            for (int k = 0; k < HF; k++) a = fmaf(x[k], sW2[k * HF + j], a);
            v[j] = fmaxf(fmaf(a, nv, sb2[j]), 0.0f);
        }
#pragma unroll
        for (int j = 0; j < HF; j++) {
            float a = sb1[j];
#pragma unroll
            for (int k = 0; k < HF; k++) a = fmaf(v[k], sW1[k * HF + j], a);
            h1[j] = fmaxf(a, 0.0f);
        }
#pragma unroll
        for (int j = 0; j < HF; j++) {
            float a = sbm[j];
#pragma unroll
            for (int k = 0; k < HF; k++) a = fmaf(h1[k], sWm[k * HF + j], a);
            h2[j] = fmaxf(a, 0.0f);
        }
        float logit = sb3;
#pragma unroll
        for (int k = 0; k < HF; k++) logit = fmaf(h2[k], sW3[k], logit);
        local = (double)logit;
    }
    red[t] = local;
    __syncthreads();
    for (int s = 128; s > 0; s >>= 1) {
        if (t < s) red[t] += red[t + s];
        __syncthreads();
    }
    if (t == 0) atomicAdd(gacc, red[0]);
}

__global__ void k_out(const double* __restrict__ acc, float* __restrict__ out, int NV) {
    out[0] = (float)(acc[0] / (double)NV);
}

// ============================================================================
// FALLBACK PATH (round-1, known-good, ~102 MB ws): global-atomic scatter.
// ============================================================================

__global__ void k_degree(const int* __restrict__ src, const int* __restrict__ dst,
                         float* __restrict__ deg_v, float* __restrict__ deg_c, int E) {
    int i = blockIdx.x * blockDim.x + threadIdx.x;
    if (i < E) {
        atomicAdd(&deg_v[src[i]], 1.0f);
        atomicAdd(&deg_c[dst[i]], 1.0f);
    }
}

__global__ void k_norm(float* __restrict__ d, int n) {
    int i = blockIdx.x * blockDim.x + threadIdx.x;
    if (i < n) d[i] = 1.0f / sqrtf(fmaxf(d[i], 1.0f));
}

__global__ void k_var_emb(const float* __restrict__ var_c, const float* __restrict__ var_x,
                          const float* __restrict__ norm_v,
                          const float* __restrict__ Wv, const float* __restrict__ bv,
                          const float* __restrict__ W2,
                          float* __restrict__ out, int NV) {
    __shared__ float sWv[2 * HF], sbv[HF], sW2[HF * HF];
    int t = threadIdx.x;
    if (t < 2 * HF) sWv[t] = Wv[t];
    if (t < HF)     sbv[t] = bv[t];
    if (t < HF * HF) sW2[t] = W2[t];
    __syncthreads();
    int i = blockIdx.x * blockDim.x + t;
    if (i >= NV) return;
    float c = var_c[i], x = var_x[i], nv = norm_v[i];
    float e[HF];
#pragma unroll
    for (int h = 0; h < HF; h++)
        e[h] = fmaxf(fmaf(c, sWv[h], fmaf(x, sWv[HF + h], sbv[h])), 0.0f) * nv;
    float* row = out + (size_t)i * ST;
#pragma unroll
    for (int j = 0; j < HF; j++) {
        float acc = 0.0f;
#pragma unroll
        for (int k = 0; k < HF; k++) acc = fmaf(e[k], sW2[k * HF + j], acc);
        row[j] = acc;
    }
}

__global__ void k_edge(const int* __restrict__ gidx, const int* __restrict__ didx,
                       const float* __restrict__ A,
                       const float* __restrict__ h, float* __restrict__ agg, int E) {
    int tid = blockIdx.x * blockDim.x + threadIdx.x;
    int e = tid / 5;
    if (e >= E) return;
    int q = tid - e * 5;
    int s = gidx[e], d = didx[e];
    float a = A[e];
    const float2 m = *(const float2*)(h + (size_t)s * ST + 2 * q);
    float* o = agg + (size_t)d * ST + 2 * q;
    atomicAdd(o,     m.x * a);
    atomicAdd(o + 1, m.y * a);
}

__global__ void k_con(float* __restrict__ buf, const float* __restrict__ norm_c,
                      const float* __restrict__ W2, const float* __restrict__ b2, int NC) {
    __shared__ float sW2[HF * HF], sb2[HF];
    int t = threadIdx.x;
    if (t < HF * HF) sW2[t] = W2[t];
    if (t < HF)      sb2[t] = b2[t];
    __syncthreads();
    int i = blockIdx.x * blockDim.x + t;
    if (i >= NC) return;
    float nc = norm_c[i];
    float* row = buf + (size_t)i * ST;
    float hc[HF];
#pragma unroll
    for (int h = 0; h < HF; h++)
        hc[h] = fmaxf(fmaf(row[h], nc, sb2[h]), 0.0f) * nc;
#pragma unroll
    for (int j = 0; j < HF; j++) {
        float acc = 0.0f;
#pragma unroll
        for (int k = 0; k < HF; k++) acc = fmaf(hc[k], sW2[k * HF + j], acc);
        row[j] = acc;
    }
}

__global__ void k_final(const float* __restrict__ agg_v, const float* __restrict__ norm_v,
                        const float* __restrict__ b2,
                        const float* __restrict__ Wo1, const float* __restrict__ bo1,
                        const float* __restrict__ Wo2, const float* __restrict__ bo2,
                        const float* __restrict__ Wo3, const float* __restrict__ bo3,
                        double* __restrict__ acc, int NV) {
    __shared__ float sb2[HF], sW1[HF * HF], sb1[HF], sW2m[HF * HF], sb2m[HF], sW3[HF];
    __shared__ float sb3;
    __shared__ double red[256];
    int t = threadIdx.x;
    if (t < HF)      sb2[t]  = b2[t];
    if (t < HF * HF) sW1[t]  = Wo1[t];
    if (t < HF)      sb1[t]  = bo1[t];
    if (t < HF * HF) sW2m[t] = Wo2[t];
    if (t < HF)      sb2m[t] = bo2[t];
    if (t < HF)      sW3[t]  = Wo3[t];
    if (t == 0)      sb3     = bo3[0];
    __syncthreads();
    int i = blockIdx.x * blockDim.x + t;
    double local = 0.0;
    if (i < NV) {
        float nv = norm_v[i];
        const float* row = agg_v + (size_t)i * ST;
        float v[HF], h1[HF], h2[HF];
#pragma unroll
        for (int h = 0; h < HF; h++) v[h] = fmaxf(fmaf(row[h], nv, sb2[h]), 0.0f);
#pragma unroll
        for (int j = 0; j < HF; j++) {
            float a = sb1[j];
#pragma unroll
            for (int k = 0; k < HF; k++) a = fmaf(v[k], sW1[k * HF + j], a);
            h1[j] = fmaxf(a, 0.0f);
        }
#pragma unroll
        for (int j = 0; j < HF; j++) {
            float a = sb2m[j];
#pragma unroll
            for (int k = 0; k < HF; k++) a = fmaf(h1[k], sW2m[k * HF + j], a);
            h2[j] = fmaxf(a, 0.0f);
        }
        float logit = sb3;
#pragma unroll
        for (int k = 0; k < HF; k++) logit = fmaf(h2[k], sW3[k], logit);
        local = (double)logit;
    }
    red[t] = local;
    __syncthreads();
    for (int s = 128; s > 0; s >>= 1) {
        if (t < s) red[t] += red[t + s];
        __syncthreads();
    }
    if (t == 0) atomicAdd(acc, red[0]);
}

// ============================================================================

extern "C" void kernel_launch(void* const* d_in, const int* in_sizes, int n_in,
                              void* d_out, int out_size, void* d_ws, size_t ws_size,
                              hipStream_t stream) {
    const float* var_c = (const float*)d_in[0];
    const float* var_x = (const float*)d_in[1];
    const float* A   = (const float*)d_in[3];
    const int*   src = (const int*)d_in[4];
    const int*   dst = (const int*)d_in[5];
    const float* Wv  = (const float*)d_in[6];
    const float* bv  = (const float*)d_in[7];
    const float* W2  = (const float*)d_in[12];
    const float* b2  = (const float*)d_in[13];
    const float* Wo1 = (const float*)d_in[14];
    const float* bo1 = (const float*)d_in[15];
    const float* Wo2 = (const float*)d_in[16];
    const float* bo2 = (const float*)d_in[17];
    const float* Wo3 = (const float*)d_in[18];
    const float* bo3 = (const float*)d_in[19];

    const int NV = in_sizes[0];
    const int NC = in_sizes[2];
    const int E  = in_sizes[3];

    // ---- pick smallest chunk count n whose layout fits ws_size ----
    auto layout_bytes = [&](int n, size_t* offs_out) -> size_t {
        size_t off = 0;
        auto alloc = [&](size_t bytes, int slot) {
            if (offs_out) offs_out[slot] = off;
            off = (off + bytes + 255) & ~(size_t)255;
        };
        int EcMax = (E + n - 1) / n;
        alloc((size_t)NV * HF * 4, 0);              // bufV
        alloc((size_t)NC * HF * 4, 1);              // bufC
        alloc((size_t)NV * 4, 2);                   // deg_v / norm_v
        alloc((size_t)NC * 4, 3);                   // deg_c
        alloc((size_t)n * SLC * NBINS * 4, 4);      // hS/offsS (in-place)
        alloc((size_t)n * SLC * NBINS * 4, 5);      // hD/offsD
        alloc((size_t)n * (NBINS + 1) * 4, 6);      // startS
        alloc((size_t)n * (NBINS + 1) * 4, 7);      // startD
        alloc((size_t)EcMax * 8, 8);                // ebuf (uint2), reused per chunk
        alloc(8, 9);                                // gacc
        return off;
    };

    int n = -1;
    size_t offs[10];
    for (int cand = 1; cand <= 8; cand++) {
        if (layout_bytes(cand, nullptr) <= ws_size) { n = cand; break; }
    }
    bool fast = (n > 0) && (NV <= (1 << 20)) && (NC <= (1 << 19)) && (E > 0);

    char* ws = (char*)d_ws;
    if (fast) {
        layout_bytes(n, offs);
        float*    bufV   = (float*)(ws + offs[0]);
        float*    bufC   = (float*)(ws + offs[1]);
        float*    deg_v  = (float*)(ws + offs[2]);
        float*    deg_c  = (float*)(ws + offs[3]);
        unsigned* hS     = (unsigned*)(ws + offs[4]);
        unsigned* hD     = (unsigned*)(ws + offs[5]);
        unsigned* startS = (unsigned*)(ws + offs[6]);
        unsigned* startD = (unsigned*)(ws + offs[7]);
        uint2*    ebuf   = (uint2*)(ws + offs[8]);
        unsigned short* sbuf = (unsigned short*)(ws + offs[8]);
        double*   gacc   = (double*)(ws + offs[9]);

        const int EcMax = (E + n - 1) / n;
        const int per   = (EcMax + SLC - 1) / SLC;
        const int NB_S  = (NV + 511) >> 9;
        const int NB_D  = (NC + 511) >> 9;

        hipMemsetAsync(bufV,  0, (size_t)NV * HF * 4, stream);
        hipMemsetAsync(bufC,  0, (size_t)NC * HF * 4, stream);
        hipMemsetAsync(deg_v, 0, (size_t)NV * 4, stream);
        hipMemsetAsync(deg_c, 0, (size_t)NC * 4, stream);
        hipMemsetAsync(gacc,  0, 8, stream);

        for (int c = 0; c < n; c++)
            k_hist<<<SLC, 512, 0, stream>>>(src, dst, hS, hD, E, EcMax, c, per);
        k_scan<<<dim3(n, 2), 1024, 0, stream>>>(hS, hD, startS, startD);

        // phase 1: deg_v
        for (int c = 0; c < n; c++) {
            k_scatU<<<SLC, 512, 0, stream>>>(src, hS, sbuf, E, EcMax, c, per);
            k_cntS<<<NB_S, 256, 0, stream>>>(sbuf, startS, deg_v, c, NV);
        }
        k_normv<<<(NV + 255) / 256, 256, 0, stream>>>(deg_v, NV);

        // phase 2: v2c aggregate -> bufC, deg_c; then con transform
        for (int c = 0; c < n; c++) {
            k_scatD<<<SLC, 512, 0, stream>>>(src, dst, A, hD, ebuf, E, EcMax, c, per);
            k_aggD<<<NB_D, 256, 0, stream>>>(ebuf, startD, var_c, var_x, deg_v,
                                             Wv, bv, bufC, deg_c, c, NC);
        }
        k_conT<<<(NC + 255) / 256, 256, 0, stream>>>(bufC, deg_c, W2, b2, NC);

        // phase 3: c2v aggregate -> bufV
        for (int c = 0; c < n; c++) {
            k_scatS<<<SLC, 512, 0, stream>>>(src, dst, A, hS, ebuf, E, EcMax, c, per);
            k_aggS<<<NB_S, 256, 0, stream>>>(ebuf, startS, bufC, bufV, c, NV);
        }

        k_final2<<<(NV + 255) / 256, 256, 0, stream>>>(bufV, deg_v, W2, b2,
                                                       Wo1, bo1, Wo2, bo2, Wo3, bo3, gacc, NV);
        k_out<<<1, 1, 0, stream>>>(gacc, (float*)d_out, NV);
    } else {
        // round-1 fallback
        const int B = 256;
        float* fbufV = (float*)ws;
        float* fbufC = (float*)(ws + (size_t)NV * ST * 4);
        float* deg_v = (float*)(ws + (size_t)(NV + NC) * ST * 4);
        float* deg_c = deg_v + NV;
        size_t acc_off = ((size_t)(NV + NC) * ST * 4 + (size_t)(NV + NC) * 4 + 7) & ~(size_t)7;
        double* acc = (double*)(ws + acc_off);

        hipMemsetAsync(deg_v, 0, (size_t)(NV + NC) * 4, stream);
        hipMemsetAsync(fbufC, 0, (size_t)NC * ST * 4, stream);
        hipMemsetAsync(acc, 0, sizeof(double), stream);

        k_degree<<<(E + B - 1) / B, B, 0, stream>>>(src, dst, deg_v, deg_c, E);
        k_norm<<<(NV + NC + B - 1) / B, B, 0, stream>>>(deg_v, NV + NC);
        k_var_emb<<<(NV + B - 1) / B, B, 0, stream>>>(var_c, var_x, deg_v, Wv, bv, W2, fbufV, NV);

        long long tE = (long long)E * 5;
        k_edge<<<(int)((tE + B - 1) / B), B, 0, stream>>>(src, dst, A, fbufV, fbufC, E);
        k_con<<<(NC + B - 1) / B, B, 0, stream>>>(fbufC, deg_c, W2, b2, NC);

        hipMemsetAsync(fbufV, 0, (size_t)NV * ST * 4, stream);
        k_edge<<<(int)((tE + B - 1) / B), B, 0, stream>>>(dst, src, A, fbufC, fbufV, E);

        k_final<<<(NV + B - 1) / B, B, 0, stream>>>(fbufV, deg_v, b2, Wo1, bo1, Wo2, bo2, Wo3, bo3, acc, NV);
        k_out<<<1, 1, 0, stream>>>(acc, (float*)d_out, NV);
    }
}

// Round 4
// 3173.579 us; speedup vs baseline: 1.6099x; 1.0150x over previous
//
#include <hip/hip_runtime.h>

#define HF 10       // feature width
#define ST 16       // fallback-path row stride
#define BST 16      // bufC padded row stride (64 B -> 1 line per random gather)
#define SLC 256     // scatter/hist slices (WGs)
#define NBINS 4096  // bins per direction (256 nodes/bin)

// ============================================================================
// FAST PATH
//   S-dir: sort-by-src-bin once (8-B payloads) -> degrees/norm_v, later reused
//          by the fused c2v aggregation + MLP + mean epilogue.
//   D-dir: chunked sort-by-dst-bin with SELF-CONTAINED 16-B payloads
//          (dlow, a*nrm_v, c, x) so v2c aggregation is pure streaming.
//   Zero global fp32 atomics anywhere on the edge path.
// ============================================================================

// ---- per-slice histogram of idx>>8 over [s_begin, s_end) ----
__global__ __launch_bounds__(1024) void k_hist(const int* __restrict__ idx,
                                               unsigned* __restrict__ hist,
                                               long long s_begin, long long s_end, int per) {
    __shared__ unsigned l[NBINS];
    int t = threadIdx.x, sl = blockIdx.x;
    for (int b = t; b < NBINS; b += 1024) l[b] = 0u;
    __syncthreads();
    long long s0 = s_begin + (long long)sl * per;
    long long s1 = s0 + per; if (s1 > s_end) s1 = s_end;
    for (long long i = s0 + t; i < s1; i += 1024)
        atomicAdd(&l[((unsigned)idx[i]) >> 8], 1u);
    __syncthreads();
    unsigned* out = hist + (size_t)sl * NBINS;
    for (int b = t; b < NBINS; b += 1024) out[b] = l[b];
}

// ---- per-bin totals over slices (coalesced column walk) ----
__global__ void k_coltot(const unsigned* __restrict__ h, unsigned* __restrict__ colT) {
    int b = blockIdx.x * 256 + threadIdx.x;
    unsigned s = 0u;
    for (int sl = 0; sl < SLC; sl++) s += h[(size_t)sl * NBINS + b];
    colT[b] = s;
}

// ---- exclusive prefix over 4096 bin totals ----
__global__ __launch_bounds__(1024) void k_prefix(const unsigned* __restrict__ colT,
                                                 unsigned* __restrict__ start) {
    __shared__ unsigned p[1024];
    int t = threadIdx.x;
    uint4 v = *(const uint4*)(colT + 4 * t);
    unsigned own = v.x + v.y + v.z + v.w;
    p[t] = own;
    __syncthreads();
    for (int off = 1; off < 1024; off <<= 1) {
        unsigned u = (t >= off) ? p[t - off] : 0u;
        __syncthreads();
        p[t] += u;
        __syncthreads();
    }
    unsigned e = p[t] - own;
    *(uint4*)(start + 4 * t) = make_uint4(e, e + v.x, e + v.x + v.y, e + v.x + v.y + v.z);
    if (t == 1023) start[NBINS] = p[1023];
}

// ---- per-slice exclusive cursors, written in place over h ----
__global__ void k_offs(unsigned* __restrict__ h, const unsigned* __restrict__ start) {
    int b = blockIdx.x * 256 + threadIdx.x;
    unsigned cur = start[b];
    for (int sl = 0; sl < SLC; sl++) {
        unsigned* cell = h + (size_t)sl * NBINS + b;
        unsigned v = *cell;
        *cell = cur;
        cur += v;
    }
}

// ---- degree scatter: src low byte only ----
__global__ __launch_bounds__(1024) void k_scatU(const int* __restrict__ src,
                                                const unsigned* __restrict__ offs,
                                                unsigned char* __restrict__ sbuf,
                                                long long E, int per) {
    __shared__ unsigned cur[NBINS];
    int t = threadIdx.x, sl = blockIdx.x;
    const unsigned* o = offs + (size_t)sl * NBINS;
    for (int b = t; b < NBINS; b += 1024) cur[b] = o[b];
    __syncthreads();
    long long s0 = (long long)sl * per;
    long long s1 = s0 + per; if (s1 > E) s1 = E;
    for (long long i = s0 + t; i < s1; i += 1024) {
        unsigned s = (unsigned)src[i];
        unsigned pos = atomicAdd(&cur[s >> 8], 1u);
        sbuf[pos] = (unsigned char)(s & 255u);
    }
}

// ---- per-bin degree count -> vcx[v] = (c, x, rsqrt(max(deg,1)), 0) ----
__global__ void k_cntS(const unsigned char* __restrict__ sbuf, const unsigned* __restrict__ startS,
                       const float* __restrict__ var_c, const float* __restrict__ var_x,
                       float4* __restrict__ vcx, int NV) {
    __shared__ unsigned cnt[256];
    int t = threadIdx.x, b = blockIdx.x;
    cnt[t] = 0u;
    __syncthreads();
    unsigned i0 = startS[b], i1 = startS[b + 1];
    for (unsigned i = i0 + t; i < i1; i += 256)
        atomicAdd(&cnt[sbuf[i]], 1u);
    __syncthreads();
    int v = b * 256 + t;
    if (v < NV)
        vcx[v] = make_float4(var_c[v], var_x[v], rsqrtf(fmaxf((float)cnt[t], 1.0f)), 0.0f);
}

// ---- D scatter: gather vcx[s] (1 line), write self-contained 16-B payload ----
__global__ __launch_bounds__(1024) void k_scatD(const int* __restrict__ src, const int* __restrict__ dst,
                                                const float* __restrict__ A,
                                                const unsigned* __restrict__ offs,
                                                const float4* __restrict__ vcx,
                                                uint4* __restrict__ ebufD,
                                                long long s_begin, long long s_end, int per) {
    __shared__ unsigned cur[NBINS];
    int t = threadIdx.x, sl = blockIdx.x;
    const unsigned* o = offs + (size_t)sl * NBINS;
    for (int b = t; b < NBINS; b += 1024) cur[b] = o[b];
    __syncthreads();
    long long s0 = s_begin + (long long)sl * per;
    long long s1 = s0 + per; if (s1 > s_end) s1 = s_end;
    for (long long i = s0 + t; i < s1; i += 2048) {
        {
            unsigned s = (unsigned)src[i], d = (unsigned)dst[i];
            float a = A[i];
            float4 g = vcx[s];
            unsigned pos = atomicAdd(&cur[d >> 8], 1u);
            ebufD[pos] = make_uint4(d & 255u, __float_as_uint(a * g.z),
                                    __float_as_uint(g.x), __float_as_uint(g.y));
        }
        long long j = i + 1024;
        if (j < s1) {
            unsigned s = (unsigned)src[j], d = (unsigned)dst[j];
            float a = A[j];
            float4 g = vcx[s];
            unsigned pos = atomicAdd(&cur[d >> 8], 1u);
            ebufD[pos] = make_uint4(d & 255u, __float_as_uint(a * g.z),
                                    __float_as_uint(g.x), __float_as_uint(g.y));
        }
    }
}

// ---- v2c aggregate: pure streaming; embed on the fly; LDS acc; RMW flush ----
__global__ void k_aggD(const uint4* __restrict__ ebufD, const unsigned* __restrict__ startD,
                       const float* __restrict__ Wv, const float* __restrict__ bv,
                       float* __restrict__ bufC, float* __restrict__ deg_c, int NC) {
    __shared__ float acc[256 * HF];
    __shared__ unsigned cnt[256];
    int t = threadIdx.x, b = blockIdx.x;
    for (int i = t; i < 256 * HF; i += 256) acc[i] = 0.0f;
    cnt[t] = 0u;
    float wv0[HF], wv1[HF], bvv[HF];
#pragma unroll
    for (int h = 0; h < HF; h++) { wv0[h] = Wv[h]; wv1[h] = Wv[HF + h]; bvv[h] = bv[h]; }
    __syncthreads();
    unsigned i0 = startD[b], i1 = startD[b + 1];
    for (unsigned i = i0 + t; i < i1; i += 256) {
        uint4 kv = ebufD[i];
        unsigned dl = kv.x;
        float anv = __uint_as_float(kv.y);
        float c   = __uint_as_float(kv.z);
        float x   = __uint_as_float(kv.w);
        float* ac = acc + dl * HF;
#pragma unroll
        for (int h = 0; h < HF; h++) {
            float e = fmaxf(fmaf(c, wv0[h], fmaf(x, wv1[h], bvv[h])), 0.0f);
            atomicAdd(ac + h, anv * e);
        }
        atomicAdd(&cnt[dl], 1u);
    }
    __syncthreads();
    int gid = b * 256 + t;
    if (gid < NC) {
        float* row = bufC + (size_t)gid * BST;
#pragma unroll
        for (int h = 0; h < HF; h++) row[h] += acc[t * HF + h];
        deg_c[gid] += (float)cnt[t];
    }
}

// ---- con transform in place (padded rows): y = relu((row@W2)*nc + b2)*nc ----
__global__ void k_conT(float* __restrict__ bufC, const float* __restrict__ deg_c,
                       const float* __restrict__ W2, const float* __restrict__ b2, int NC) {
    __shared__ float sW[HF * HF], sb[HF];
    int t = threadIdx.x;
    if (t < HF * HF) sW[t] = W2[t];
    if (t < HF)      sb[t] = b2[t];
    __syncthreads();
    int i = blockIdx.x * 256 + t;
    if (i >= NC) return;
    float nc = rsqrtf(fmaxf(deg_c[i], 1.0f));
    float* row = bufC + (size_t)i * BST;
    float x[HF];
#pragma unroll
    for (int h = 0; h < HF; h++) x[h] = row[h];
#pragma unroll
    for (int j = 0; j < HF; j++) {
        float a = 0.0f;
#pragma unroll
        for (int k = 0; k < HF; k++) a = fmaf(x[k], sW[k * HF + j], a);
        row[j] = fmaxf(fmaf(a, nc, sb[j]), 0.0f) * nc;
    }
}

// ---- S scatter: key=(slow8<<19)|dst19, payload A ----
__global__ __launch_bounds__(1024) void k_scatS(const int* __restrict__ src, const int* __restrict__ dst,
                                                const float* __restrict__ A,
                                                const unsigned* __restrict__ offs,
                                                uint2* __restrict__ ebufS,
                                                long long E, int per) {
    __shared__ unsigned cur[NBINS];
    int t = threadIdx.x, sl = blockIdx.x;
    const unsigned* o = offs + (size_t)sl * NBINS;
    for (int b = t; b < NBINS; b += 1024) cur[b] = o[b];
    __syncthreads();
    long long s0 = (long long)sl * per;
    long long s1 = s0 + per; if (s1 > E) s1 = E;
    for (long long i = s0 + t; i < s1; i += 1024) {
        unsigned s = (unsigned)src[i], d = (unsigned)dst[i];
        float a = A[i];
        unsigned pos = atomicAdd(&cur[s >> 8], 1u);
        ebufS[pos] = make_uint2(((s & 255u) << 19) | d, __float_as_uint(a));
    }
}

// ---- fused c2v aggregate + @W2 + norm + MLP + mean (single full pass) ----
__global__ void k_aggS(const uint2* __restrict__ ebufS, const unsigned* __restrict__ startS,
                       const float* __restrict__ bufC, const float4* __restrict__ vcx,
                       const float* __restrict__ W2, const float* __restrict__ b2,
                       const float* __restrict__ Wo1, const float* __restrict__ bo1,
                       const float* __restrict__ Wo2, const float* __restrict__ bo2,
                       const float* __restrict__ Wo3, const float* __restrict__ bo3,
                       double* __restrict__ gacc, int NV) {
    __shared__ float acc[256 * HF];
    __shared__ float sW2[HF * HF], sb2[HF], sW1[HF * HF], sb1[HF], sWm[HF * HF], sbm[HF], sW3[HF];
    __shared__ float sb3;
    __shared__ double red[256];
    int t = threadIdx.x, b = blockIdx.x;
    for (int i = t; i < 256 * HF; i += 256) acc[i] = 0.0f;
    if (t < HF * HF) { sW2[t] = W2[t]; sW1[t] = Wo1[t]; sWm[t] = Wo2[t]; }
    if (t < HF)      { sb2[t] = b2[t]; sb1[t] = bo1[t]; sbm[t] = bo2[t]; sW3[t] = Wo3[t]; }
    if (t == 0)      sb3 = bo3[0];
    __syncthreads();
    unsigned i0 = startS[b], i1 = startS[b + 1];
    for (unsigned i = i0 + t; i < i1; i += 512) {
        uint2 kv0 = ebufS[i];
        unsigned j = i + 256;
        bool hv1 = (j < i1);
        uint2 kv1 = hv1 ? ebufS[j] : make_uint2(0u, 0u);
        {
            const float* yr = bufC + (size_t)(kv0.x & 0x7FFFFu) * BST;
            float4 p = *(const float4*)yr;
            float4 q = *(const float4*)(yr + 4);
            float2 r = *(const float2*)(yr + 8);
            float a = __uint_as_float(kv0.y);
            float* ac = acc + (kv0.x >> 19) * HF;
            atomicAdd(ac + 0, a * p.x); atomicAdd(ac + 1, a * p.y);
            atomicAdd(ac + 2, a * p.z); atomicAdd(ac + 3, a * p.w);
            atomicAdd(ac + 4, a * q.x); atomicAdd(ac + 5, a * q.y);
            atomicAdd(ac + 6, a * q.z); atomicAdd(ac + 7, a * q.w);
            atomicAdd(ac + 8, a * r.x); atomicAdd(ac + 9, a * r.y);
        }
        if (hv1) {
            const float* yr = bufC + (size_t)(kv1.x & 0x7FFFFu) * BST;
            float4 p = *(const float4*)yr;
            float4 q = *(const float4*)(yr + 4);
            float2 r = *(const float2*)(yr + 8);
            float a = __uint_as_float(kv1.y);
            float* ac = acc + (kv1.x >> 19) * HF;
            atomicAdd(ac + 0, a * p.x); atomicAdd(ac + 1, a * p.y);
            atomicAdd(ac + 2, a * p.z); atomicAdd(ac + 3, a * p.w);
            atomicAdd(ac + 4, a * q.x); atomicAdd(ac + 5, a * q.y);
            atomicAdd(ac + 6, a * q.z); atomicAdd(ac + 7, a * q.w);
            atomicAdd(ac + 8, a * r.x); atomicAdd(ac + 9, a * r.y);
        }
    }
    __syncthreads();
    double local = 0.0;
    int v = b * 256 + t;
    if (v < NV) {
        float nv = vcx[v].z;
        float x[HF], hv[HF], h1[HF], h2[HF];
#pragma unroll
        for (int h = 0; h < HF; h++) x[h] = acc[t * HF + h];
#pragma unroll
        for (int j = 0; j < HF; j++) {
            float a = 0.0f;
#pragma unroll
            for (int k = 0; k < HF; k++) a = fmaf(x[k], sW2[k * HF + j], a);
            hv[j] = fmaxf(fmaf(a, nv, sb2[j]), 0.0f);
        }
#pragma unroll
        for (int j = 0; j < HF; j++) {
            float a = sb1[j];
#pragma unroll
            for (int k = 0; k < HF; k++) a = fmaf(hv[k], sW1[k * HF + j], a);
            h1[j] = fmaxf(a, 0.0f);
        }
#pragma unroll
        for (int j = 0; j < HF; j++) {
            float a = sbm[j];
#pragma unroll
            for (int k = 0; k < HF; k++) a = fmaf(h1[k], sWm[k * HF + j], a);
            h2[j] = fmaxf(a, 0.0f);
        }
        float logit = sb3;
#pragma unroll
        for (int k = 0; k < HF; k++) logit = fmaf(h2[k], sW3[k], logit);
        local = (double)logit;
    }
    red[t] = local;
    __syncthreads();
    for (int s = 128; s > 0; s >>= 1) {
        if (t < s) red[t] += red[t + s];
        __syncthreads();
    }
    if (t == 0) atomicAdd(gacc, red[0]);
}

__global__ void k_out(const double* __restrict__ acc, float* __restrict__ out, int NV) {
    out[0] = (float)(acc[0] / (double)NV);
}

// ============================================================================
// FALLBACK PATH (round-1, known-good, ~102 MB ws): global-atomic scatter.
// ============================================================================

__global__ void k_degree(const int* __restrict__ src, const int* __restrict__ dst,
                         float* __restrict__ deg_v, float* __restrict__ deg_c, int E) {
    int i = blockIdx.x * blockDim.x + threadIdx.x;
    if (i < E) {
        atomicAdd(&deg_v[src[i]], 1.0f);
        atomicAdd(&deg_c[dst[i]], 1.0f);
    }
}

__global__ void k_norm(float* __restrict__ d, int n) {
    int i = blockIdx.x * blockDim.x + threadIdx.x;
    if (i < n) d[i] = 1.0f / sqrtf(fmaxf(d[i], 1.0f));
}

__global__ void k_var_emb(const float* __restrict__ var_c, const float* __restrict__ var_x,
                          const float* __restrict__ norm_v,
                          const float* __restrict__ Wv, const float* __restrict__ bv,
                          const float* __restrict__ W2,
                          float* __restrict__ out, int NV) {
    __shared__ float sWv[2 * HF], sbv[HF], sW2[HF * HF];
    int t = threadIdx.x;
    if (t < 2 * HF) sWv[t] = Wv[t];
    if (t < HF)     sbv[t] = bv[t];
    if (t < HF * HF) sW2[t] = W2[t];
    __syncthreads();
    int i = blockIdx.x * blockDim.x + t;
    if (i >= NV) return;
    float c = var_c[i], x = var_x[i], nv = norm_v[i];
    float e[HF];
#pragma unroll
    for (int h = 0; h < HF; h++)
        e[h] = fmaxf(fmaf(c, sWv[h], fmaf(x, sWv[HF + h], sbv[h])), 0.0f) * nv;
    float* row = out + (size_t)i * ST;
#pragma unroll
    for (int j = 0; j < HF; j++) {
        float acc = 0.0f;
#pragma unroll
        for (int k = 0; k < HF; k++) acc = fmaf(e[k], sW2[k * HF + j], acc);
        row[j] = acc;
    }
}

__global__ void k_edge(const int* __restrict__ gidx, const int* __restrict__ didx,
                       const float* __restrict__ A,
                       const float* __restrict__ h, float* __restrict__ agg, int E) {
    int tid = blockIdx.x * blockDim.x + threadIdx.x;
    int e = tid / 5;
    if (e >= E) return;
    int q = tid - e * 5;
    int s = gidx[e], d = didx[e];
    float a = A[e];
    const float2 m = *(const float2*)(h + (size_t)s * ST + 2 * q);
    float* o = agg + (size_t)d * ST + 2 * q;
    atomicAdd(o,     m.x * a);
    atomicAdd(o + 1, m.y * a);
}

__global__ void k_con(float* __restrict__ buf, const float* __restrict__ norm_c,
                      const float* __restrict__ W2, const float* __restrict__ b2, int NC) {
    __shared__ float sW2[HF * HF], sb2[HF];
    int t = threadIdx.x;
    if (t < HF * HF) sW2[t] = W2[t];
    if (t < HF)      sb2[t] = b2[t];
    __syncthreads();
    int i = blockIdx.x * blockDim.x + t;
    if (i >= NC) return;
    float nc = norm_c[i];
    float* row = buf + (size_t)i * ST;
    float hc[HF];
#pragma unroll
    for (int h = 0; h < HF; h++)
        hc[h] = fmaxf(fmaf(row[h], nc, sb2[h]), 0.0f) * nc;
#pragma unroll
    for (int j = 0; j < HF; j++) {
        float acc = 0.0f;
#pragma unroll
        for (int k = 0; k < HF; k++) acc = fmaf(hc[k], sW2[k * HF + j], acc);
        row[j] = acc;
    }
}

__global__ void k_final(const float* __restrict__ agg_v, const float* __restrict__ norm_v,
                        const float* __restrict__ b2,
                        const float* __restrict__ Wo1, const float* __restrict__ bo1,
                        const float* __restrict__ Wo2, const float* __restrict__ bo2,
                        const float* __restrict__ Wo3, const float* __restrict__ bo3,
                        double* __restrict__ acc, int NV) {
    __shared__ float sb2[HF], sW1[HF * HF], sb1[HF], sW2m[HF * HF], sb2m[HF], sW3[HF];
    __shared__ float sb3;
    __shared__ double red[256];
    int t = threadIdx.x;
    if (t < HF)      sb2[t]  = b2[t];
    if (t < HF * HF) sW1[t]  = Wo1[t];
    if (t < HF)      sb1[t]  = bo1[t];
    if (t < HF * HF) sW2m[t] = Wo2[t];
    if (t < HF)      sb2m[t] = bo2[t];
    if (t < HF)      sW3[t]  = Wo3[t];
    if (t == 0)      sb3     = bo3[0];
    __syncthreads();
    int i = blockIdx.x * blockDim.x + t;
    double local = 0.0;
    if (i < NV) {
        float nv = norm_v[i];
        const float* row = agg_v + (size_t)i * ST;
        float v[HF], h1[HF], h2[HF];
#pragma unroll
        for (int h = 0; h < HF; h++) v[h] = fmaxf(fmaf(row[h], nv, sb2[h]), 0.0f);
#pragma unroll
        for (int j = 0; j < HF; j++) {
            float a = sb1[j];
#pragma unroll
            for (int k = 0; k < HF; k++) a = fmaf(v[k], sW1[k * HF + j], a);
            h1[j] = fmaxf(a, 0.0f);
        }
#pragma unroll
        for (int j = 0; j < HF; j++) {
            float a = sb2m[j];
#pragma unroll
            for (int k = 0; k < HF; k++) a = fmaf(h1[k], sW2m[k * HF + j], a);
            h2[j] = fmaxf(a, 0.0f);
        }
        float logit = sb3;
#pragma unroll
        for (int k = 0; k < HF; k++) logit = fmaf(h2[k], sW3[k], logit);
        local = (double)logit;
    }
    red[t] = local;
    __syncthreads();
    for (int s = 128; s > 0; s >>= 1) {
        if (t < s) red[t] += red[t + s];
        __syncthreads();
    }
    if (t == 0) atomicAdd(acc, red[0]);
}

// ============================================================================

extern "C" void kernel_launch(void* const* d_in, const int* in_sizes, int n_in,
                              void* d_out, int out_size, void* d_ws, size_t ws_size,
                              hipStream_t stream) {
    const float* var_c = (const float*)d_in[0];
    const float* var_x = (const float*)d_in[1];
    const float* A   = (const float*)d_in[3];
    const int*   src = (const int*)d_in[4];
    const int*   dst = (const int*)d_in[5];
    const float* Wv  = (const float*)d_in[6];
    const float* bv  = (const float*)d_in[7];
    const float* W2  = (const float*)d_in[12];
    const float* b2  = (const float*)d_in[13];
    const float* Wo1 = (const float*)d_in[14];
    const float* bo1 = (const float*)d_in[15];
    const float* Wo2 = (const float*)d_in[16];
    const float* bo2 = (const float*)d_in[17];
    const float* Wo3 = (const float*)d_in[18];
    const float* bo3 = (const float*)d_in[19];

    const int NV = in_sizes[0];
    const int NC = in_sizes[2];
    const int E  = in_sizes[3];

    // ---- fast-path layout (ebuf shared by sbuf / ebufD / ebufS over time) ----
    auto layout_bytes = [&](int nD, size_t* offs_out) -> size_t {
        size_t off = 0;
        auto alloc = [&](size_t bytes, int slot) {
            if (offs_out) offs_out[slot] = off;
            off = (off + bytes + 255) & ~(size_t)255;
        };
        size_t EcMax = ((size_t)E + nD - 1) / nD;
        size_t ebuf_sz = (size_t)E * 8;                  // ebufS (8 B)
        if (EcMax * 16 > ebuf_sz) ebuf_sz = EcMax * 16;  // ebufD (16 B), sbuf (1 B) smaller
        alloc((size_t)NC * BST * 4, 0);       // bufC
        alloc((size_t)NV * 16, 1);            // vcx (float4)
        alloc((size_t)NC * 4, 2);             // deg_c
        alloc((size_t)SLC * NBINS * 4, 3);    // hS / offsS
        alloc((size_t)SLC * NBINS * 4, 4);    // hD / offsD (reused per chunk)
        alloc((size_t)NBINS * 4, 5);          // colT
        alloc((size_t)(NBINS + 1) * 4, 6);    // startS
        alloc((size_t)(NBINS + 1) * 4, 7);    // startD
        alloc(8, 8);                          // gacc
        alloc(ebuf_sz, 9);                    // ebuf
        return off;
    };

    int nD = 0;
    size_t offs[10];
    if (layout_bytes(1, nullptr) <= ws_size) nD = 1;
    else if (layout_bytes(2, nullptr) <= ws_size) nD = 2;
    bool fast = (nD > 0) && (NV <= (1 << 20)) && (NC <= (1 << 19)) && (E > 0);

    char* ws = (char*)d_ws;
    if (fast) {
        layout_bytes(nD, offs);
        float*    bufC   = (float*)(ws + offs[0]);
        float4*   vcx    = (float4*)(ws + offs[1]);
        float*    deg_c  = (float*)(ws + offs[2]);
        unsigned* hS     = (unsigned*)(ws + offs[3]);
        unsigned* hD     = (unsigned*)(ws + offs[4]);
        unsigned* colT   = (unsigned*)(ws + offs[5]);
        unsigned* startS = (unsigned*)(ws + offs[6]);
        unsigned* startD = (unsigned*)(ws + offs[7]);
        double*   gacc   = (double*)(ws + offs[8]);
        unsigned char* sbuf = (unsigned char*)(ws + offs[9]);
        uint4*    ebufD  = (uint4*)(ws + offs[9]);
        uint2*    ebufS  = (uint2*)(ws + offs[9]);

        const long long EcMax = ((long long)E + nD - 1) / nD;
        const int perS = (int)(((long long)E + SLC - 1) / SLC);
        const int perD = (int)((EcMax + SLC - 1) / SLC);
        const int NB_S = (NV + 255) >> 8;
        const int NB_C = (NC + 255) >> 8;

        hipMemsetAsync(bufC,  0, (size_t)NC * BST * 4, stream);
        hipMemsetAsync(deg_c, 0, (size_t)NC * 4, stream);
        hipMemsetAsync(gacc,  0, 8, stream);

        // S cursors (kept valid through the whole launch)
        k_hist<<<SLC, 1024, 0, stream>>>(src, hS, 0, E, perS);
        k_coltot<<<NBINS / 256, 256, 0, stream>>>(hS, colT);
        k_prefix<<<1, 1024, 0, stream>>>(colT, startS);
        k_offs<<<NBINS / 256, 256, 0, stream>>>(hS, startS);

        // degrees -> vcx
        k_scatU<<<SLC, 1024, 0, stream>>>(src, hS, sbuf, E, perS);
        k_cntS<<<NB_S, 256, 0, stream>>>(sbuf, startS, var_c, var_x, vcx, NV);

        // D chunks: hist -> cursors -> 16-B scatter -> streaming aggregate
        for (int c = 0; c < nD; c++) {
            long long cb = (long long)c * EcMax;
            long long ce = cb + EcMax; if (ce > E) ce = E;
            k_hist<<<SLC, 1024, 0, stream>>>(dst, hD, cb, ce, perD);
            k_coltot<<<NBINS / 256, 256, 0, stream>>>(hD, colT);
            k_prefix<<<1, 1024, 0, stream>>>(colT, startD);
            k_offs<<<NBINS / 256, 256, 0, stream>>>(hD, startD);
            k_scatD<<<SLC, 1024, 0, stream>>>(src, dst, A, hD, vcx, ebufD, cb, ce, perD);
            k_aggD<<<NB_C, 256, 0, stream>>>(ebufD, startD, Wv, bv, bufC, deg_c, NC);
        }
        k_conT<<<NB_C, 256, 0, stream>>>(bufC, deg_c, W2, b2, NC);

        // S scatter + fused aggregate/MLP/mean
        k_scatS<<<SLC, 1024, 0, stream>>>(src, dst, A, hS, ebufS, E, perS);
        k_aggS<<<NB_S, 256, 0, stream>>>(ebufS, startS, bufC, vcx, W2, b2,
                                         Wo1, bo1, Wo2, bo2, Wo3, bo3, gacc, NV);
        k_out<<<1, 1, 0, stream>>>(gacc, (float*)d_out, NV);
    } else {
        // round-1 fallback
        const int B = 256;
        float* fbufV = (float*)ws;
        float* fbufC = (float*)(ws + (size_t)NV * ST * 4);
        float* deg_v = (float*)(ws + (size_t)(NV + NC) * ST * 4);
        float* deg_c = deg_v + NV;
        size_t acc_off = ((size_t)(NV + NC) * ST * 4 + (size_t)(NV + NC) * 4 + 7) & ~(size_t)7;
        double* acc = (double*)(ws + acc_off);

        hipMemsetAsync(deg_v, 0, (size_t)(NV + NC) * 4, stream);
        hipMemsetAsync(fbufC, 0, (size_t)NC * ST * 4, stream);
        hipMemsetAsync(acc, 0, sizeof(double), stream);

        k_degree<<<(E + B - 1) / B, B, 0, stream>>>(src, dst, deg_v, deg_c, E);
        k_norm<<<(NV + NC + B - 1) / B, B, 0, stream>>>(deg_v, NV + NC);
        k_var_emb<<<(NV + B - 1) / B, B, 0, stream>>>(var_c, var_x, deg_v, Wv, bv, W2, fbufV, NV);

        long long tE = (long long)E * 5;
        k_edge<<<(int)((tE + B - 1) / B), B, 0, stream>>>(src, dst, A, fbufV, fbufC, E);
        k_con<<<(NC + B - 1) / B, B, 0, stream>>>(fbufC, deg_c, W2, b2, NC);

        hipMemsetAsync(fbufV, 0, (size_t)NV * ST * 4, stream);
        k_edge<<<(int)((tE + B - 1) / B), B, 0, stream>>>(dst, src, A, fbufC, fbufV, E);

        k_final<<<(NV + B - 1) / B, B, 0, stream>>>(fbufV, deg_v, b2, Wo1, bo1, Wo2, bo2, Wo3, bo3, acc, NV);
        k_out<<<1, 1, 0, stream>>>(acc, (float*)d_out, NV);
    }
}

// Round 5
// 3151.667 us; speedup vs baseline: 1.6211x; 1.0070x over previous
//
#include <hip/hip_runtime.h>

#define HF 10       // feature width
#define ST 16       // fallback-path row stride
#define BST 16      // bufC padded row stride (64 B -> 1 line per random gather)
#define SLC 256     // scatter/hist slices (WGs)
#define NBINS 4096  // bins per direction (256 nodes/bin)

// ============================================================================
// FAST PATH
//   S-dir: sort-by-src-bin once (8-B payloads) -> degrees/norm_v, later reused
//          by the fused c2v aggregation + MLP + mean epilogue.
//   D-dir: sort-by-dst-bin with SELF-CONTAINED 16-B payloads (dlow, a*nrm, c, x)
//          so v2c aggregation is pure streaming.
//   Gather kernels (scatD: vcx[src], aggS: bufC[dst]) use ILP-4 phase-separated
//   loops: 4 independent line gathers in flight before any dependent op.
//   Zero global fp32 atomics anywhere on the edge path.
// ============================================================================

// ---- per-slice histogram of idx>>8 over [s_begin, s_end) ----
__global__ __launch_bounds__(1024) void k_hist(const int* __restrict__ idx,
                                               unsigned* __restrict__ hist,
                                               long long s_begin, long long s_end, int per) {
    __shared__ unsigned l[NBINS];
    int t = threadIdx.x, sl = blockIdx.x;
    for (int b = t; b < NBINS; b += 1024) l[b] = 0u;
    __syncthreads();
    long long s0 = s_begin + (long long)sl * per;
    long long s1 = s0 + per; if (s1 > s_end) s1 = s_end;
    for (long long i = s0 + t; i < s1; i += 1024)
        atomicAdd(&l[((unsigned)idx[i]) >> 8], 1u);
    __syncthreads();
    unsigned* out = hist + (size_t)sl * NBINS;
    for (int b = t; b < NBINS; b += 1024) out[b] = l[b];
}

// ---- per-bin totals over slices (coalesced column walk) ----
__global__ void k_coltot(const unsigned* __restrict__ h, unsigned* __restrict__ colT) {
    int b = blockIdx.x * 256 + threadIdx.x;
    unsigned s = 0u;
    for (int sl = 0; sl < SLC; sl++) s += h[(size_t)sl * NBINS + b];
    colT[b] = s;
}

// ---- exclusive prefix over 4096 bin totals ----
__global__ __launch_bounds__(1024) void k_prefix(const unsigned* __restrict__ colT,
                                                 unsigned* __restrict__ start) {
    __shared__ unsigned p[1024];
    int t = threadIdx.x;
    uint4 v = *(const uint4*)(colT + 4 * t);
    unsigned own = v.x + v.y + v.z + v.w;
    p[t] = own;
    __syncthreads();
    for (int off = 1; off < 1024; off <<= 1) {
        unsigned u = (t >= off) ? p[t - off] : 0u;
        __syncthreads();
        p[t] += u;
        __syncthreads();
    }
    unsigned e = p[t] - own;
    *(uint4*)(start + 4 * t) = make_uint4(e, e + v.x, e + v.x + v.y, e + v.x + v.y + v.z);
    if (t == 1023) start[NBINS] = p[1023];
}

// ---- per-slice exclusive cursors, written in place over h ----
__global__ void k_offs(unsigned* __restrict__ h, const unsigned* __restrict__ start) {
    int b = blockIdx.x * 256 + threadIdx.x;
    unsigned cur = start[b];
    for (int sl = 0; sl < SLC; sl++) {
        unsigned* cell = h + (size_t)sl * NBINS + b;
        unsigned v = *cell;
        *cell = cur;
        cur += v;
    }
}

// ---- degree scatter: src low byte only ----
__global__ __launch_bounds__(1024) void k_scatU(const int* __restrict__ src,
                                                const unsigned* __restrict__ offs,
                                                unsigned char* __restrict__ sbuf,
                                                long long E, int per) {
    __shared__ unsigned cur[NBINS];
    int t = threadIdx.x, sl = blockIdx.x;
    const unsigned* o = offs + (size_t)sl * NBINS;
    for (int b = t; b < NBINS; b += 1024) cur[b] = o[b];
    __syncthreads();
    long long s0 = (long long)sl * per;
    long long s1 = s0 + per; if (s1 > E) s1 = E;
    for (long long i = s0 + t; i < s1; i += 1024) {
        unsigned s = (unsigned)src[i];
        unsigned pos = atomicAdd(&cur[s >> 8], 1u);
        sbuf[pos] = (unsigned char)(s & 255u);
    }
}

// ---- per-bin degree count -> vcx[v] = (c, x, rsqrt(max(deg,1)), 0) ----
__global__ void k_cntS(const unsigned char* __restrict__ sbuf, const unsigned* __restrict__ startS,
                       const float* __restrict__ var_c, const float* __restrict__ var_x,
                       float4* __restrict__ vcx, int NV) {
    __shared__ unsigned cnt[256];
    int t = threadIdx.x, b = blockIdx.x;
    cnt[t] = 0u;
    __syncthreads();
    unsigned i0 = startS[b], i1 = startS[b + 1];
    for (unsigned i = i0 + t; i < i1; i += 256)
        atomicAdd(&cnt[sbuf[i]], 1u);
    __syncthreads();
    int v = b * 256 + t;
    if (v < NV)
        vcx[v] = make_float4(var_c[v], var_x[v], rsqrtf(fmaxf((float)cnt[t], 1.0f)), 0.0f);
}

// ---- D scatter: ILP-4 phase-separated vcx gather, 16-B self-contained payload ----
__global__ __launch_bounds__(1024) void k_scatD(const int* __restrict__ src, const int* __restrict__ dst,
                                                const float* __restrict__ A,
                                                const unsigned* __restrict__ offs,
                                                const float4* __restrict__ vcx,
                                                uint4* __restrict__ ebufD,
                                                long long s_begin, long long s_end, int per) {
    __shared__ unsigned cur[NBINS];
    int t = threadIdx.x, sl = blockIdx.x;
    const unsigned* o = offs + (size_t)sl * NBINS;
    for (int b = t; b < NBINS; b += 1024) cur[b] = o[b];
    __syncthreads();
    long long s0 = s_begin + (long long)sl * per;
    long long s1 = s0 + per; if (s1 > s_end) s1 = s_end;
    for (long long i = s0 + t; i < s1; i += 4096) {
        unsigned sv[4], dv[4]; float av[4]; bool hv[4];
#pragma unroll
        for (int j = 0; j < 4; j++) {
            long long idx = i + (long long)j * 1024;
            hv[j] = idx < s1;
            if (hv[j]) { sv[j] = (unsigned)src[idx]; dv[j] = (unsigned)dst[idx]; av[j] = A[idx]; }
            else       { sv[j] = 0u; dv[j] = 0u; av[j] = 0.0f; }
        }
        float4 g[4];
#pragma unroll
        for (int j = 0; j < 4; j++)
            if (hv[j]) g[j] = vcx[sv[j]];
#pragma unroll
        for (int j = 0; j < 4; j++) {
            if (!hv[j]) continue;
            unsigned pos = atomicAdd(&cur[dv[j] >> 8], 1u);
            ebufD[pos] = make_uint4(dv[j] & 255u, __float_as_uint(av[j] * g[j].z),
                                    __float_as_uint(g[j].x), __float_as_uint(g[j].y));
        }
    }
}

// ---- v2c aggregate: pure streaming; embed on the fly; LDS acc; RMW flush ----
__global__ void k_aggD(const uint4* __restrict__ ebufD, const unsigned* __restrict__ startD,
                       const float* __restrict__ Wv, const float* __restrict__ bv,
                       float* __restrict__ bufC, float* __restrict__ deg_c, int NC) {
    __shared__ float acc[256 * HF];
    __shared__ unsigned cnt[256];
    int t = threadIdx.x, b = blockIdx.x;
    for (int i = t; i < 256 * HF; i += 256) acc[i] = 0.0f;
    cnt[t] = 0u;
    float wv0[HF], wv1[HF], bvv[HF];
#pragma unroll
    for (int h = 0; h < HF; h++) { wv0[h] = Wv[h]; wv1[h] = Wv[HF + h]; bvv[h] = bv[h]; }
    __syncthreads();
    unsigned i0 = startD[b], i1 = startD[b + 1];
    for (unsigned i = i0 + t; i < i1; i += 256) {
        uint4 kv = ebufD[i];
        unsigned dl = kv.x;
        float anv = __uint_as_float(kv.y);
        float c   = __uint_as_float(kv.z);
        float x   = __uint_as_float(kv.w);
        float* ac = acc + dl * HF;
#pragma unroll
        for (int h = 0; h < HF; h++) {
            float e = fmaxf(fmaf(c, wv0[h], fmaf(x, wv1[h], bvv[h])), 0.0f);
            atomicAdd(ac + h, anv * e);
        }
        atomicAdd(&cnt[dl], 1u);
    }
    __syncthreads();
    int gid = b * 256 + t;
    if (gid < NC) {
        float* row = bufC + (size_t)gid * BST;
#pragma unroll
        for (int h = 0; h < HF; h++) row[h] += acc[t * HF + h];
        deg_c[gid] += (float)cnt[t];
    }
}

// ---- con transform in place (padded rows): y = relu((row@W2)*nc + b2)*nc ----
__global__ void k_conT(float* __restrict__ bufC, const float* __restrict__ deg_c,
                       const float* __restrict__ W2, const float* __restrict__ b2, int NC) {
    __shared__ float sW[HF * HF], sb[HF];
    int t = threadIdx.x;
    if (t < HF * HF) sW[t] = W2[t];
    if (t < HF)      sb[t] = b2[t];
    __syncthreads();
    int i = blockIdx.x * 256 + t;
    if (i >= NC) return;
    float nc = rsqrtf(fmaxf(deg_c[i], 1.0f));
    float* row = bufC + (size_t)i * BST;
    float x[HF];
#pragma unroll
    for (int h = 0; h < HF; h++) x[h] = row[h];
#pragma unroll
    for (int j = 0; j < HF; j++) {
        float a = 0.0f;
#pragma unroll
        for (int k = 0; k < HF; k++) a = fmaf(x[k], sW[k * HF + j], a);
        row[j] = fmaxf(fmaf(a, nc, sb[j]), 0.0f) * nc;
    }
}

// ---- S scatter: key=(slow8<<19)|dst19, payload A ----
__global__ __launch_bounds__(1024) void k_scatS(const int* __restrict__ src, const int* __restrict__ dst,
                                                const float* __restrict__ A,
                                                const unsigned* __restrict__ offs,
                                                uint2* __restrict__ ebufS,
                                                long long E, int per) {
    __shared__ unsigned cur[NBINS];
    int t = threadIdx.x, sl = blockIdx.x;
    const unsigned* o = offs + (size_t)sl * NBINS;
    for (int b = t; b < NBINS; b += 1024) cur[b] = o[b];
    __syncthreads();
    long long s0 = (long long)sl * per;
    long long s1 = s0 + per; if (s1 > E) s1 = E;
    for (long long i = s0 + t; i < s1; i += 1024) {
        unsigned s = (unsigned)src[i], d = (unsigned)dst[i];
        float a = A[i];
        unsigned pos = atomicAdd(&cur[s >> 8], 1u);
        ebufS[pos] = make_uint2(((s & 255u) << 19) | d, __float_as_uint(a));
    }
}

// ---- fused c2v aggregate + @W2 + norm + MLP + mean; ILP-4 batched y-gathers ----
__global__ void k_aggS(const uint2* __restrict__ ebufS, const unsigned* __restrict__ startS,
                       const float* __restrict__ bufC, const float4* __restrict__ vcx,
                       const float* __restrict__ W2, const float* __restrict__ b2,
                       const float* __restrict__ Wo1, const float* __restrict__ bo1,
                       const float* __restrict__ Wo2, const float* __restrict__ bo2,
                       const float* __restrict__ Wo3, const float* __restrict__ bo3,
                       double* __restrict__ gacc, int NV) {
    __shared__ float acc[256 * HF];
    __shared__ float sW2[HF * HF], sb2[HF], sW1[HF * HF], sb1[HF], sWm[HF * HF], sbm[HF], sW3[HF];
    __shared__ float sb3;
    __shared__ double red[256];
    int t = threadIdx.x, b = blockIdx.x;
    for (int i = t; i < 256 * HF; i += 256) acc[i] = 0.0f;
    if (t < HF * HF) { sW2[t] = W2[t]; sW1[t] = Wo1[t]; sWm[t] = Wo2[t]; }
    if (t < HF)      { sb2[t] = b2[t]; sb1[t] = bo1[t]; sbm[t] = bo2[t]; sW3[t] = Wo3[t]; }
    if (t == 0)      sb3 = bo3[0];
    __syncthreads();
    unsigned i0 = startS[b], i1 = startS[b + 1];
    for (unsigned i = i0 + t; i < i1; i += 1024) {
        // phase 1: stream 4 payloads
        uint2 kv[4]; bool hv[4];
#pragma unroll
        for (int j = 0; j < 4; j++) {
            unsigned idx = i + (unsigned)j * 256u;
            hv[j] = idx < i1;
            kv[j] = hv[j] ? ebufS[idx] : make_uint2(0u, 0u);
        }
        // phase 2: 4 independent 64-B line gathers in flight
        float4 p[4], q[4]; float2 r[4];
#pragma unroll
        for (int j = 0; j < 4; j++) {
            if (hv[j]) {
                const float* yr = bufC + (size_t)(kv[j].x & 0x7FFFFu) * BST;
                p[j] = *(const float4*)yr;
                q[j] = *(const float4*)(yr + 4);
                r[j] = *(const float2*)(yr + 8);
            }
        }
        // phase 3: dependent LDS accumulation
#pragma unroll
        for (int j = 0; j < 4; j++) {
            if (!hv[j]) continue;
            float a = __uint_as_float(kv[j].y);
            float* ac = acc + (kv[j].x >> 19) * HF;
            atomicAdd(ac + 0, a * p[j].x); atomicAdd(ac + 1, a * p[j].y);
            atomicAdd(ac + 2, a * p[j].z); atomicAdd(ac + 3, a * p[j].w);
            atomicAdd(ac + 4, a * q[j].x); atomicAdd(ac + 5, a * q[j].y);
            atomicAdd(ac + 6, a * q[j].z); atomicAdd(ac + 7, a * q[j].w);
            atomicAdd(ac + 8, a * r[j].x); atomicAdd(ac + 9, a * r[j].y);
        }
    }
    __syncthreads();
    double local = 0.0;
    int v = b * 256 + t;
    if (v < NV) {
        float nv = vcx[v].z;
        float x[HF], hvv[HF], h1[HF], h2[HF];
#pragma unroll
        for (int h = 0; h < HF; h++) x[h] = acc[t * HF + h];
#pragma unroll
        for (int j = 0; j < HF; j++) {
            float a = 0.0f;
#pragma unroll
            for (int k = 0; k < HF; k++) a = fmaf(x[k], sW2[k * HF + j], a);
            hvv[j] = fmaxf(fmaf(a, nv, sb2[j]), 0.0f);
        }
#pragma unroll
        for (int j = 0; j < HF; j++) {
            float a = sb1[j];
#pragma unroll
            for (int k = 0; k < HF; k++) a = fmaf(hvv[k], sW1[k * HF + j], a);
            h1[j] = fmaxf(a, 0.0f);
        }
#pragma unroll
        for (int j = 0; j < HF; j++) {
            float a = sbm[j];
#pragma unroll
            for (int k = 0; k < HF; k++) a = fmaf(h1[k], sWm[k * HF + j], a);
            h2[j] = fmaxf(a, 0.0f);
        }
        float logit = sb3;
#pragma unroll
        for (int k = 0; k < HF; k++) logit = fmaf(h2[k], sW3[k], logit);
        local = (double)logit;
    }
    red[t] = local;
    __syncthreads();
    for (int s = 128; s > 0; s >>= 1) {
        if (t < s) red[t] += red[t + s];
        __syncthreads();
    }
    if (t == 0) atomicAdd(gacc, red[0]);
}

__global__ void k_out(const double* __restrict__ acc, float* __restrict__ out, int NV) {
    out[0] = (float)(acc[0] / (double)NV);
}

// ============================================================================
// FALLBACK PATH (round-1, known-good, ~102 MB ws): global-atomic scatter.
// ============================================================================

__global__ void k_degree(const int* __restrict__ src, const int* __restrict__ dst,
                         float* __restrict__ deg_v, float* __restrict__ deg_c, int E) {
    int i = blockIdx.x * blockDim.x + threadIdx.x;
    if (i < E) {
        atomicAdd(&deg_v[src[i]], 1.0f);
        atomicAdd(&deg_c[dst[i]], 1.0f);
    }
}

__global__ void k_norm(float* __restrict__ d, int n) {
    int i = blockIdx.x * blockDim.x + threadIdx.x;
    if (i < n) d[i] = 1.0f / sqrtf(fmaxf(d[i], 1.0f));
}

__global__ void k_var_emb(const float* __restrict__ var_c, const float* __restrict__ var_x,
                          const float* __restrict__ norm_v,
                          const float* __restrict__ Wv, const float* __restrict__ bv,
                          const float* __restrict__ W2,
                          float* __restrict__ out, int NV) {
    __shared__ float sWv[2 * HF], sbv[HF], sW2[HF * HF];
    int t = threadIdx.x;
    if (t < 2 * HF) sWv[t] = Wv[t];
    if (t < HF)     sbv[t] = bv[t];
    if (t < HF * HF) sW2[t] = W2[t];
    __syncthreads();
    int i = blockIdx.x * blockDim.x + t;
    if (i >= NV) return;
    float c = var_c[i], x = var_x[i], nv = norm_v[i];
    float e[HF];
#pragma unroll
    for (int h = 0; h < HF; h++)
        e[h] = fmaxf(fmaf(c, sWv[h], fmaf(x, sWv[HF + h], sbv[h])), 0.0f) * nv;
    float* row = out + (size_t)i * ST;
#pragma unroll
    for (int j = 0; j < HF; j++) {
        float acc = 0.0f;
#pragma unroll
        for (int k = 0; k < HF; k++) acc = fmaf(e[k], sW2[k * HF + j], acc);
        row[j] = acc;
    }
}

__global__ void k_edge(const int* __restrict__ gidx, const int* __restrict__ didx,
                       const float* __restrict__ A,
                       const float* __restrict__ h, float* __restrict__ agg, int E) {
    int tid = blockIdx.x * blockDim.x + threadIdx.x;
    int e = tid / 5;
    if (e >= E) return;
    int q = tid - e * 5;
    int s = gidx[e], d = didx[e];
    float a = A[e];
    const float2 m = *(const float2*)(h + (size_t)s * ST + 2 * q);
    float* o = agg + (size_t)d * ST + 2 * q;
    atomicAdd(o,     m.x * a);
    atomicAdd(o + 1, m.y * a);
}

__global__ void k_con(float* __restrict__ buf, const float* __restrict__ norm_c,
                      const float* __restrict__ W2, const float* __restrict__ b2, int NC) {
    __shared__ float sW2[HF * HF], sb2[HF];
    int t = threadIdx.x;
    if (t < HF * HF) sW2[t] = W2[t];
    if (t < HF)      sb2[t] = b2[t];
    __syncthreads();
    int i = blockIdx.x * blockDim.x + t;
    if (i >= NC) return;
    float nc = norm_c[i];
    float* row = buf + (size_t)i * ST;
    float hc[HF];
#pragma unroll
    for (int h = 0; h < HF; h++)
        hc[h] = fmaxf(fmaf(row[h], nc, sb2[h]), 0.0f) * nc;
#pragma unroll
    for (int j = 0; j < HF; j++) {
        float acc = 0.0f;
#pragma unroll
        for (int k = 0; k < HF; k++) acc = fmaf(hc[k], sW2[k * HF + j], acc);
        row[j] = acc;
    }
}

__global__ void k_final(const float* __restrict__ agg_v, const float* __restrict__ norm_v,
                        const float* __restrict__ b2,
                        const float* __restrict__ Wo1, const float* __restrict__ bo1,
                        const float* __restrict__ Wo2, const float* __restrict__ bo2,
                        const float* __restrict__ Wo3, const float* __restrict__ bo3,
                        double* __restrict__ acc, int NV) {
    __shared__ float sb2[HF], sW1[HF * HF], sb1[HF], sW2m[HF * HF], sb2m[HF], sW3[HF];
    __shared__ float sb3;
    __shared__ double red[256];
    int t = threadIdx.x;
    if (t < HF)      sb2[t]  = b2[t];
    if (t < HF * HF) sW1[t]  = Wo1[t];
    if (t < HF)      sb1[t]  = bo1[t];
    if (t < HF * HF) sW2m[t] = Wo2[t];
    if (t < HF)      sb2m[t] = bo2[t];
    if (t < HF)      sW3[t]  = Wo3[t];
    if (t == 0)      sb3     = bo3[0];
    __syncthreads();
    int i = blockIdx.x * blockDim.x + t;
    double local = 0.0;
    if (i < NV) {
        float nv = norm_v[i];
        const float* row = agg_v + (size_t)i * ST;
        float v[HF], h1[HF], h2[HF];
#pragma unroll
        for (int h = 0; h < HF; h++) v[h] = fmaxf(fmaf(row[h], nv, sb2[h]), 0.0f);
#pragma unroll
        for (int j = 0; j < HF; j++) {
            float a = sb1[j];
#pragma unroll
            for (int k = 0; k < HF; k++) a = fmaf(v[k], sW1[k * HF + j], a);
            h1[j] = fmaxf(a, 0.0f);
        }
#pragma unroll
        for (int j = 0; j < HF; j++) {
            float a = sb2m[j];
#pragma unroll
            for (int k = 0; k < HF; k++) a = fmaf(h1[k], sW2m[k * HF + j], a);
            h2[j] = fmaxf(a, 0.0f);
        }
        float logit = sb3;
#pragma unroll
        for (int k = 0; k < HF; k++) logit = fmaf(h2[k], sW3[k], logit);
        local = (double)logit;
    }
    red[t] = local;
    __syncthreads();
    for (int s = 128; s > 0; s >>= 1) {
        if (t < s) red[t] += red[t + s];
        __syncthreads();
    }
    if (t == 0) atomicAdd(acc, red[0]);
}

// ============================================================================

extern "C" void kernel_launch(void* const* d_in, const int* in_sizes, int n_in,
                              void* d_out, int out_size, void* d_ws, size_t ws_size,
                              hipStream_t stream) {
    const float* var_c = (const float*)d_in[0];
    const float* var_x = (const float*)d_in[1];
    const float* A   = (const float*)d_in[3];
    const int*   src = (const int*)d_in[4];
    const int*   dst = (const int*)d_in[5];
    const float* Wv  = (const float*)d_in[6];
    const float* bv  = (const float*)d_in[7];
    const float* W2  = (const float*)d_in[12];
    const float* b2  = (const float*)d_in[13];
    const float* Wo1 = (const float*)d_in[14];
    const float* bo1 = (const float*)d_in[15];
    const float* Wo2 = (const float*)d_in[16];
    const float* bo2 = (const float*)d_in[17];
    const float* Wo3 = (const float*)d_in[18];
    const float* bo3 = (const float*)d_in[19];

    const int NV = in_sizes[0];
    const int NC = in_sizes[2];
    const int E  = in_sizes[3];

    // ---- fast-path layout (ebuf shared by sbuf / ebufD / ebufS over time) ----
    auto layout_bytes = [&](int nD, size_t* offs_out) -> size_t {
        size_t off = 0;
        auto alloc = [&](size_t bytes, int slot) {
            if (offs_out) offs_out[slot] = off;
            off = (off + bytes + 255) & ~(size_t)255;
        };
        size_t EcMax = ((size_t)E + nD - 1) / nD;
        size_t ebuf_sz = (size_t)E * 8;                  // ebufS (8 B)
        if (EcMax * 16 > ebuf_sz) ebuf_sz = EcMax * 16;  // ebufD (16 B), sbuf (1 B) smaller
        alloc((size_t)NC * BST * 4, 0);       // bufC
        alloc((size_t)NV * 16, 1);            // vcx (float4)
        alloc((size_t)NC * 4, 2);             // deg_c
        alloc((size_t)SLC * NBINS * 4, 3);    // hS / offsS
        alloc((size_t)SLC * NBINS * 4, 4);    // hD / offsD (reused per chunk)
        alloc((size_t)NBINS * 4, 5);          // colT
        alloc((size_t)(NBINS + 1) * 4, 6);    // startS
        alloc((size_t)(NBINS + 1) * 4, 7);    // startD
        alloc(8, 8);                          // gacc
        alloc(ebuf_sz, 9);                    // ebuf
        return off;
    };

    int nD = 0;
    size_t offs[10];
    if (layout_bytes(1, nullptr) <= ws_size) nD = 1;
    else if (layout_bytes(2, nullptr) <= ws_size) nD = 2;
    bool fast = (nD > 0) && (NV <= (1 << 20)) && (NC <= (1 << 19)) && (E > 0);

    char* ws = (char*)d_ws;
    if (fast) {
        layout_bytes(nD, offs);
        float*    bufC   = (float*)(ws + offs[0]);
        float4*   vcx    = (float4*)(ws + offs[1]);
        float*    deg_c  = (float*)(ws + offs[2]);
        unsigned* hS     = (unsigned*)(ws + offs[3]);
        unsigned* hD     = (unsigned*)(ws + offs[4]);
        unsigned* colT   = (unsigned*)(ws + offs[5]);
        unsigned* startS = (unsigned*)(ws + offs[6]);
        unsigned* startD = (unsigned*)(ws + offs[7]);
        double*   gacc   = (double*)(ws + offs[8]);
        unsigned char* sbuf = (unsigned char*)(ws + offs[9]);
        uint4*    ebufD  = (uint4*)(ws + offs[9]);
        uint2*    ebufS  = (uint2*)(ws + offs[9]);

        const long long EcMax = ((long long)E + nD - 1) / nD;
        const int perS = (int)(((long long)E + SLC - 1) / SLC);
        const int perD = (int)((EcMax + SLC - 1) / SLC);
        const int NB_S = (NV + 255) >> 8;
        const int NB_C = (NC + 255) >> 8;

        hipMemsetAsync(bufC,  0, (size_t)NC * BST * 4, stream);
        hipMemsetAsync(deg_c, 0, (size_t)NC * 4, stream);
        hipMemsetAsync(gacc,  0, 8, stream);

        // S cursors (kept valid through the whole launch)
        k_hist<<<SLC, 1024, 0, stream>>>(src, hS, 0, E, perS);
        k_coltot<<<NBINS / 256, 256, 0, stream>>>(hS, colT);
        k_prefix<<<1, 1024, 0, stream>>>(colT, startS);
        k_offs<<<NBINS / 256, 256, 0, stream>>>(hS, startS);

        // degrees -> vcx
        k_scatU<<<SLC, 1024, 0, stream>>>(src, hS, sbuf, E, perS);
        k_cntS<<<NB_S, 256, 0, stream>>>(sbuf, startS, var_c, var_x, vcx, NV);

        // D chunks: hist -> cursors -> 16-B scatter -> streaming aggregate
        for (int c = 0; c < nD; c++) {
            long long cb = (long long)c * EcMax;
            long long ce = cb + EcMax; if (ce > E) ce = E;
            k_hist<<<SLC, 1024, 0, stream>>>(dst, hD, cb, ce, perD);
            k_coltot<<<NBINS / 256, 256, 0, stream>>>(hD, colT);
            k_prefix<<<1, 1024, 0, stream>>>(colT, startD);
            k_offs<<<NBINS / 256, 256, 0, stream>>>(hD, startD);
            k_scatD<<<SLC, 1024, 0, stream>>>(src, dst, A, hD, vcx, ebufD, cb, ce, perD);
            k_aggD<<<NB_C, 256, 0, stream>>>(ebufD, startD, Wv, bv, bufC, deg_c, NC);
        }
        k_conT<<<NB_C, 256, 0, stream>>>(bufC, deg_c, W2, b2, NC);

        // S scatter + fused aggregate/MLP/mean
        k_scatS<<<SLC, 1024, 0, stream>>>(src, dst, A, hS, ebufS, E, perS);
        k_aggS<<<NB_S, 256, 0, stream>>>(ebufS, startS, bufC, vcx, W2, b2,
                                         Wo1, bo1, Wo2, bo2, Wo3, bo3, gacc, NV);
        k_out<<<1, 1, 0, stream>>>(gacc, (float*)d_out, NV);
    } else {
        // round-1 fallback
        const int B = 256;
        float* fbufV = (float*)ws;
        float* fbufC = (float*)(ws + (size_t)NV * ST * 4);
        float* deg_v = (float*)(ws + (size_t)(NV + NC) * ST * 4);
        float* deg_c = deg_v + NV;
        size_t acc_off = ((size_t)(NV + NC) * ST * 4 + (size_t)(NV + NC) * 4 + 7) & ~(size_t)7;
        double* acc = (double*)(ws + acc_off);

        hipMemsetAsync(deg_v, 0, (size_t)(NV + NC) * 4, stream);
        hipMemsetAsync(fbufC, 0, (size_t)NC * ST * 4, stream);
        hipMemsetAsync(acc, 0, sizeof(double), stream);

        k_degree<<<(E + B - 1) / B, B, 0, stream>>>(src, dst, deg_v, deg_c, E);
        k_norm<<<(NV + NC + B - 1) / B, B, 0, stream>>>(deg_v, NV + NC);
        k_var_emb<<<(NV + B - 1) / B, B, 0, stream>>>(var_c, var_x, deg_v, Wv, bv, W2, fbufV, NV);

        long long tE = (long long)E * 5;
        k_edge<<<(int)((tE + B - 1) / B), B, 0, stream>>>(src, dst, A, fbufV, fbufC, E);
        k_con<<<(NC + B - 1) / B, B, 0, stream>>>(fbufC, deg_c, W2, b2, NC);

        hipMemsetAsync(fbufV, 0, (size_t)NV * ST * 4, stream);
        k_edge<<<(int)((tE + B - 1) / B), B, 0, stream>>>(dst, src, A, fbufC, fbufV, E);

        k_final<<<(NV + B - 1) / B, B, 0, stream>>>(fbufV, deg_v, b2, Wo1, bo1, Wo2, bo2, Wo3, bo3, acc, NV);
        k_out<<<1, 1, 0, stream>>>(acc, (float*)d_out, NV);
    }
}

// Round 6
// 2998.910 us; speedup vs baseline: 1.7037x; 1.0509x over previous
//
#include <hip/hip_runtime.h>

#define HF 10       // feature width
#define ST 16       // fallback-path row stride
#define BST 16      // bufC padded row stride (64 B -> 1 line per random gather)
#define SLC 256     // scatter/hist slices (WGs)
#define NBINS 4096  // bins per direction (256 nodes/bin)

// ============================================================================
// FAST PATH (request-rate aware):
//   1) sort edges by src-bin (8-B payloads, key=(slow8<<19)|dst19)  [k_scatS]
//   2) degrees/norm from sorted keys (streaming)                    [k_cntS2]
//   3) D-phase (chunked): sort by dst-bin w/ self-contained 16-B payloads
//      (dlow, a*nrm, c, x); streaming aggregation into bufC         [k_scatD/k_aggD]
//   4) con transform                                                [k_conT]
//   5) fused c2v aggregate + @W2 + MLP + mean, with COOPERATIVE 4-lane
//      row gather: one 64-B line request per edge                   [k_aggS]
//   Zero global fp32 atomics on the edge path.
// ============================================================================

// ---- per-slice histogram of idx>>8 over [s_begin, s_end) ----
__global__ __launch_bounds__(1024) void k_hist(const int* __restrict__ idx,
                                               unsigned* __restrict__ hist,
                                               long long s_begin, long long s_end, int per) {
    __shared__ unsigned l[NBINS];
    int t = threadIdx.x, sl = blockIdx.x;
    for (int b = t; b < NBINS; b += 1024) l[b] = 0u;
    __syncthreads();
    long long s0 = s_begin + (long long)sl * per;
    long long s1 = s0 + per; if (s1 > s_end) s1 = s_end;
    for (long long i = s0 + t; i < s1; i += 1024)
        atomicAdd(&l[((unsigned)idx[i]) >> 8], 1u);
    __syncthreads();
    unsigned* out = hist + (size_t)sl * NBINS;
    for (int b = t; b < NBINS; b += 1024) out[b] = l[b];
}

// ---- per-bin totals over slices (coalesced column walk) ----
__global__ void k_coltot(const unsigned* __restrict__ h, unsigned* __restrict__ colT) {
    int b = blockIdx.x * 256 + threadIdx.x;
    unsigned s = 0u;
    for (int sl = 0; sl < SLC; sl++) s += h[(size_t)sl * NBINS + b];
    colT[b] = s;
}

// ---- exclusive prefix over 4096 bin totals ----
__global__ __launch_bounds__(1024) void k_prefix(const unsigned* __restrict__ colT,
                                                 unsigned* __restrict__ start) {
    __shared__ unsigned p[1024];
    int t = threadIdx.x;
    uint4 v = *(const uint4*)(colT + 4 * t);
    unsigned own = v.x + v.y + v.z + v.w;
    p[t] = own;
    __syncthreads();
    for (int off = 1; off < 1024; off <<= 1) {
        unsigned u = (t >= off) ? p[t - off] : 0u;
        __syncthreads();
        p[t] += u;
        __syncthreads();
    }
    unsigned e = p[t] - own;
    *(uint4*)(start + 4 * t) = make_uint4(e, e + v.x, e + v.x + v.y, e + v.x + v.y + v.z);
    if (t == 1023) start[NBINS] = p[1023];
}

// ---- per-slice exclusive cursors, written in place over h ----
__global__ void k_offs(unsigned* __restrict__ h, const unsigned* __restrict__ start) {
    int b = blockIdx.x * 256 + threadIdx.x;
    unsigned cur = start[b];
    for (int sl = 0; sl < SLC; sl++) {
        unsigned* cell = h + (size_t)sl * NBINS + b;
        unsigned v = *cell;
        *cell = cur;
        cur += v;
    }
}

// ---- S scatter: key=(slow8<<19)|dst19, payload A ----
__global__ __launch_bounds__(1024) void k_scatS(const int* __restrict__ src, const int* __restrict__ dst,
                                                const float* __restrict__ A,
                                                const unsigned* __restrict__ offs,
                                                uint2* __restrict__ ebufS,
                                                long long E, int per) {
    __shared__ unsigned cur[NBINS];
    int t = threadIdx.x, sl = blockIdx.x;
    const unsigned* o = offs + (size_t)sl * NBINS;
    for (int b = t; b < NBINS; b += 1024) cur[b] = o[b];
    __syncthreads();
    long long s0 = (long long)sl * per;
    long long s1 = s0 + per; if (s1 > E) s1 = E;
    for (long long i = s0 + t; i < s1; i += 1024) {
        unsigned s = (unsigned)src[i], d = (unsigned)dst[i];
        float a = A[i];
        unsigned pos = atomicAdd(&cur[s >> 8], 1u);
        ebufS[pos] = make_uint2(((s & 255u) << 19) | d, __float_as_uint(a));
    }
}

// ---- degrees from sorted S keys (streaming) -> vcx[v]=(c,x,rsqrt(max(deg,1)),0) ----
__global__ void k_cntS2(const uint2* __restrict__ ebufS, const unsigned* __restrict__ startS,
                        const float* __restrict__ var_c, const float* __restrict__ var_x,
                        float4* __restrict__ vcx, int NV) {
    __shared__ unsigned cnt[256];
    int t = threadIdx.x, b = blockIdx.x;
    cnt[t] = 0u;
    __syncthreads();
    unsigned i0 = startS[b], i1 = startS[b + 1];
    for (unsigned i = i0 + t; i < i1; i += 256)
        atomicAdd(&cnt[ebufS[i].x >> 19], 1u);
    __syncthreads();
    int v = b * 256 + t;
    if (v < NV)
        vcx[v] = make_float4(var_c[v], var_x[v], rsqrtf(fmaxf((float)cnt[t], 1.0f)), 0.0f);
}

// ---- D scatter: ILP-4 phase-separated vcx gather, 16-B self-contained payload ----
__global__ __launch_bounds__(1024) void k_scatD(const int* __restrict__ src, const int* __restrict__ dst,
                                                const float* __restrict__ A,
                                                const unsigned* __restrict__ offs,
                                                const float4* __restrict__ vcx,
                                                uint4* __restrict__ ebufD,
                                                long long s_begin, long long s_end, int per) {
    __shared__ unsigned cur[NBINS];
    int t = threadIdx.x, sl = blockIdx.x;
    const unsigned* o = offs + (size_t)sl * NBINS;
    for (int b = t; b < NBINS; b += 1024) cur[b] = o[b];
    __syncthreads();
    long long s0 = s_begin + (long long)sl * per;
    long long s1 = s0 + per; if (s1 > s_end) s1 = s_end;
    for (long long i = s0 + t; i < s1; i += 4096) {
        unsigned sv[4], dv[4]; float av[4]; bool hv[4];
#pragma unroll
        for (int j = 0; j < 4; j++) {
            long long idx = i + (long long)j * 1024;
            hv[j] = idx < s1;
            if (hv[j]) { sv[j] = (unsigned)src[idx]; dv[j] = (unsigned)dst[idx]; av[j] = A[idx]; }
            else       { sv[j] = 0u; dv[j] = 0u; av[j] = 0.0f; }
        }
        float4 g[4];
#pragma unroll
        for (int j = 0; j < 4; j++)
            if (hv[j]) g[j] = vcx[sv[j]];
#pragma unroll
        for (int j = 0; j < 4; j++) {
            if (!hv[j]) continue;
            unsigned pos = atomicAdd(&cur[dv[j] >> 8], 1u);
            ebufD[pos] = make_uint4(dv[j] & 255u, __float_as_uint(av[j] * g[j].z),
                                    __float_as_uint(g[j].x), __float_as_uint(g[j].y));
        }
    }
}

// ---- v2c aggregate: pure streaming; embed on the fly; LDS acc; RMW flush ----
__global__ void k_aggD(const uint4* __restrict__ ebufD, const unsigned* __restrict__ startD,
                       const float* __restrict__ Wv, const float* __restrict__ bv,
                       float* __restrict__ bufC, float* __restrict__ deg_c, int NC) {
    __shared__ float acc[256 * HF];
    __shared__ unsigned cnt[256];
    int t = threadIdx.x, b = blockIdx.x;
    for (int i = t; i < 256 * HF; i += 256) acc[i] = 0.0f;
    cnt[t] = 0u;
    float wv0[HF], wv1[HF], bvv[HF];
#pragma unroll
    for (int h = 0; h < HF; h++) { wv0[h] = Wv[h]; wv1[h] = Wv[HF + h]; bvv[h] = bv[h]; }
    __syncthreads();
    unsigned i0 = startD[b], i1 = startD[b + 1];
    for (unsigned i = i0 + t; i < i1; i += 256) {
        uint4 kv = ebufD[i];
        unsigned dl = kv.x;
        float anv = __uint_as_float(kv.y);
        float c   = __uint_as_float(kv.z);
        float x   = __uint_as_float(kv.w);
        float* ac = acc + dl * HF;
#pragma unroll
        for (int h = 0; h < HF; h++) {
            float e = fmaxf(fmaf(c, wv0[h], fmaf(x, wv1[h], bvv[h])), 0.0f);
            atomicAdd(ac + h, anv * e);
        }
        atomicAdd(&cnt[dl], 1u);
    }
    __syncthreads();
    int gid = b * 256 + t;
    if (gid < NC) {
        float* row = bufC + (size_t)gid * BST;
#pragma unroll
        for (int h = 0; h < HF; h++) row[h] += acc[t * HF + h];
        deg_c[gid] += (float)cnt[t];
    }
}

// ---- con transform in place (padded rows): y = relu((row@W2)*nc + b2)*nc ----
__global__ void k_conT(float* __restrict__ bufC, const float* __restrict__ deg_c,
                       const float* __restrict__ W2, const float* __restrict__ b2, int NC) {
    __shared__ float sW[HF * HF], sb[HF];
    int t = threadIdx.x;
    if (t < HF * HF) sW[t] = W2[t];
    if (t < HF)      sb[t] = b2[t];
    __syncthreads();
    int i = blockIdx.x * 256 + t;
    if (i >= NC) return;
    float nc = rsqrtf(fmaxf(deg_c[i], 1.0f));
    float* row = bufC + (size_t)i * BST;
    float x[HF];
#pragma unroll
    for (int h = 0; h < HF; h++) x[h] = row[h];
#pragma unroll
    for (int j = 0; j < HF; j++) {
        float a = 0.0f;
#pragma unroll
        for (int k = 0; k < HF; k++) a = fmaf(x[k], sW[k * HF + j], a);
        row[j] = fmaxf(fmaf(a, nc, sb[j]), 0.0f) * nc;
    }
}

// ---- fused c2v aggregate + @W2 + norm + MLP + mean.
// Cooperative gather: 4 lanes per edge, each loads float4 at row+4q ->
// the wave instruction coalesces the 4 same-line lanes: ONE line req/edge. ----
__global__ void k_aggS(const uint2* __restrict__ ebufS, const unsigned* __restrict__ startS,
                       const float* __restrict__ bufC, const float4* __restrict__ vcx,
                       const float* __restrict__ W2, const float* __restrict__ b2,
                       const float* __restrict__ Wo1, const float* __restrict__ bo1,
                       const float* __restrict__ Wo2, const float* __restrict__ bo2,
                       const float* __restrict__ Wo3, const float* __restrict__ bo3,
                       double* __restrict__ gacc, int NV) {
    __shared__ float acc[256 * HF];
    __shared__ float sW2[HF * HF], sb2[HF], sW1[HF * HF], sb1[HF], sWm[HF * HF], sbm[HF], sW3[HF];
    __shared__ float sb3;
    __shared__ double red[256];
    int t = threadIdx.x, b = blockIdx.x;
    for (int i = t; i < 256 * HF; i += 256) acc[i] = 0.0f;
    if (t < HF * HF) { sW2[t] = W2[t]; sW1[t] = Wo1[t]; sWm[t] = Wo2[t]; }
    if (t < HF)      { sb2[t] = b2[t]; sb1[t] = bo1[t]; sbm[t] = bo2[t]; sW3[t] = Wo3[t]; }
    if (t == 0)      sb3 = bo3[0];
    __syncthreads();
    unsigned i0 = startS[b], i1 = startS[b + 1];
    int grp = t >> 2;          // 64 edge-groups per block iteration
    int q   = t & 3;           // quarter of the 64-B row
    int nq  = (q < 2) ? 4 : (q == 2 ? 2 : 0);   // feature count in this quarter
    for (unsigned base = i0; base < i1; base += 64) {
        unsigned e = base + (unsigned)grp;
        bool ok = e < i1;
        uint2 kv = ok ? ebufS[e] : make_uint2(0u, 0u);
        float4 y = make_float4(0.f, 0.f, 0.f, 0.f);
        if (ok) y = *(const float4*)(bufC + (size_t)(kv.x & 0x7FFFFu) * BST + 4 * q);
        if (ok && nq) {
            float a = __uint_as_float(kv.y);
            float* ac = acc + (kv.x >> 19) * HF + 4 * q;
            atomicAdd(ac + 0, a * y.x);
            atomicAdd(ac + 1, a * y.y);
            if (nq == 4) {
                atomicAdd(ac + 2, a * y.z);
                atomicAdd(ac + 3, a * y.w);
            }
        }
    }
    __syncthreads();
    double local = 0.0;
    int v = b * 256 + t;
    if (v < NV) {
        float nv = vcx[v].z;
        float x[HF], hvv[HF], h1[HF], h2[HF];
#pragma unroll
        for (int h = 0; h < HF; h++) x[h] = acc[t * HF + h];
#pragma unroll
        for (int j = 0; j < HF; j++) {
            float a = 0.0f;
#pragma unroll
            for (int k = 0; k < HF; k++) a = fmaf(x[k], sW2[k * HF + j], a);
            hvv[j] = fmaxf(fmaf(a, nv, sb2[j]), 0.0f);
        }
#pragma unroll
        for (int j = 0; j < HF; j++) {
            float a = sb1[j];
#pragma unroll
            for (int k = 0; k < HF; k++) a = fmaf(hvv[k], sW1[k * HF + j], a);
            h1[j] = fmaxf(a, 0.0f);
        }
#pragma unroll
        for (int j = 0; j < HF; j++) {
            float a = sbm[j];
#pragma unroll
            for (int k = 0; k < HF; k++) a = fmaf(h1[k], sWm[k * HF + j], a);
            h2[j] = fmaxf(a, 0.0f);
        }
        float logit = sb3;
#pragma unroll
        for (int k = 0; k < HF; k++) logit = fmaf(h2[k], sW3[k], logit);
        local = (double)logit;
    }
    red[t] = local;
    __syncthreads();
    for (int s = 128; s > 0; s >>= 1) {
        if (t < s) red[t] += red[t + s];
        __syncthreads();
    }
    if (t == 0) atomicAdd(gacc, red[0]);
}

__global__ void k_out(const double* __restrict__ acc, float* __restrict__ out, int NV) {
    out[0] = (float)(acc[0] / (double)NV);
}

// ============================================================================
// FALLBACK PATH (round-1, known-good, ~102 MB ws): global-atomic scatter.
// ============================================================================

__global__ void k_degree(const int* __restrict__ src, const int* __restrict__ dst,
                         float* __restrict__ deg_v, float* __restrict__ deg_c, int E) {
    int i = blockIdx.x * blockDim.x + threadIdx.x;
    if (i < E) {
        atomicAdd(&deg_v[src[i]], 1.0f);
        atomicAdd(&deg_c[dst[i]], 1.0f);
    }
}

__global__ void k_norm(float* __restrict__ d, int n) {
    int i = blockIdx.x * blockDim.x + threadIdx.x;
    if (i < n) d[i] = 1.0f / sqrtf(fmaxf(d[i], 1.0f));
}

__global__ void k_var_emb(const float* __restrict__ var_c, const float* __restrict__ var_x,
                          const float* __restrict__ norm_v,
                          const float* __restrict__ Wv, const float* __restrict__ bv,
                          const float* __restrict__ W2,
                          float* __restrict__ out, int NV) {
    __shared__ float sWv[2 * HF], sbv[HF], sW2[HF * HF];
    int t = threadIdx.x;
    if (t < 2 * HF) sWv[t] = Wv[t];
    if (t < HF)     sbv[t] = bv[t];
    if (t < HF * HF) sW2[t] = W2[t];
    __syncthreads();
    int i = blockIdx.x * blockDim.x + t;
    if (i >= NV) return;
    float c = var_c[i], x = var_x[i], nv = norm_v[i];
    float e[HF];
#pragma unroll
    for (int h = 0; h < HF; h++)
        e[h] = fmaxf(fmaf(c, sWv[h], fmaf(x, sWv[HF + h], sbv[h])), 0.0f) * nv;
    float* row = out + (size_t)i * ST;
#pragma unroll
    for (int j = 0; j < HF; j++) {
        float acc = 0.0f;
#pragma unroll
        for (int k = 0; k < HF; k++) acc = fmaf(e[k], sW2[k * HF + j], acc);
        row[j] = acc;
    }
}

__global__ void k_edge(const int* __restrict__ gidx, const int* __restrict__ didx,
                       const float* __restrict__ A,
                       const float* __restrict__ h, float* __restrict__ agg, int E) {
    int tid = blockIdx.x * blockDim.x + threadIdx.x;
    int e = tid / 5;
    if (e >= E) return;
    int q = tid - e * 5;
    int s = gidx[e], d = didx[e];
    float a = A[e];
    const float2 m = *(const float2*)(h + (size_t)s * ST + 2 * q);
    float* o = agg + (size_t)d * ST + 2 * q;
    atomicAdd(o,     m.x * a);
    atomicAdd(o + 1, m.y * a);
}

__global__ void k_con(float* __restrict__ buf, const float* __restrict__ norm_c,
                      const float* __restrict__ W2, const float* __restrict__ b2, int NC) {
    __shared__ float sW2[HF * HF], sb2[HF];
    int t = threadIdx.x;
    if (t < HF * HF) sW2[t] = W2[t];
    if (t < HF)      sb2[t] = b2[t];
    __syncthreads();
    int i = blockIdx.x * blockDim.x + t;
    if (i >= NC) return;
    float nc = norm_c[i];
    float* row = buf + (size_t)i * ST;
    float hc[HF];
#pragma unroll
    for (int h = 0; h < HF; h++)
        hc[h] = fmaxf(fmaf(row[h], nc, sb2[h]), 0.0f) * nc;
#pragma unroll
    for (int j = 0; j < HF; j++) {
        float acc = 0.0f;
#pragma unroll
        for (int k = 0; k < HF; k++) acc = fmaf(hc[k], sW2[k * HF + j], acc);
        row[j] = acc;
    }
}

__global__ void k_final(const float* __restrict__ agg_v, const float* __restrict__ norm_v,
                        const float* __restrict__ b2,
                        const float* __restrict__ Wo1, const float* __restrict__ bo1,
                        const float* __restrict__ Wo2, const float* __restrict__ bo2,
                        const float* __restrict__ Wo3, const float* __restrict__ bo3,
                        double* __restrict__ acc, int NV) {
    __shared__ float sb2[HF], sW1[HF * HF], sb1[HF], sW2m[HF * HF], sb2m[HF], sW3[HF];
    __shared__ float sb3;
    __shared__ double red[256];
    int t = threadIdx.x;
    if (t < HF)      sb2[t]  = b2[t];
    if (t < HF * HF) sW1[t]  = Wo1[t];
    if (t < HF)      sb1[t]  = bo1[t];
    if (t < HF * HF) sW2m[t] = Wo2[t];
    if (t < HF)      sb2m[t] = bo2[t];
    if (t < HF)      sW3[t]  = Wo3[t];
    if (t == 0)      sb3     = bo3[0];
    __syncthreads();
    int i = blockIdx.x * blockDim.x + t;
    double local = 0.0;
    if (i < NV) {
        float nv = norm_v[i];
        const float* row = agg_v + (size_t)i * ST;
        float v[HF], h1[HF], h2[HF];
#pragma unroll
        for (int h = 0; h < HF; h++) v[h] = fmaxf(fmaf(row[h], nv, sb2[h]), 0.0f);
#pragma unroll
        for (int j = 0; j < HF; j++) {
            float a = sb1[j];
#pragma unroll
            for (int k = 0; k < HF; k++) a = fmaf(v[k], sW1[k * HF + j], a);
            h1[j] = fmaxf(a, 0.0f);
        }
#pragma unroll
        for (int j = 0; j < HF; j++) {
            float a = sb2m[j];
#pragma unroll
            for (int k = 0; k < HF; k++) a = fmaf(h1[k], sW2m[k * HF + j], a);
            h2[j] = fmaxf(a, 0.0f);
        }
        float logit = sb3;
#pragma unroll
        for (int k = 0; k < HF; k++) logit = fmaf(h2[k], sW3[k], logit);
        local = (double)logit;
    }
    red[t] = local;
    __syncthreads();
    for (int s = 128; s > 0; s >>= 1) {
        if (t < s) red[t] += red[t + s];
        __syncthreads();
    }
    if (t == 0) atomicAdd(acc, red[0]);
}

// ============================================================================

extern "C" void kernel_launch(void* const* d_in, const int* in_sizes, int n_in,
                              void* d_out, int out_size, void* d_ws, size_t ws_size,
                              hipStream_t stream) {
    const float* var_c = (const float*)d_in[0];
    const float* var_x = (const float*)d_in[1];
    const float* A   = (const float*)d_in[3];
    const int*   src = (const int*)d_in[4];
    const int*   dst = (const int*)d_in[5];
    const float* Wv  = (const float*)d_in[6];
    const float* bv  = (const float*)d_in[7];
    const float* W2  = (const float*)d_in[12];
    const float* b2  = (const float*)d_in[13];
    const float* Wo1 = (const float*)d_in[14];
    const float* bo1 = (const float*)d_in[15];
    const float* Wo2 = (const float*)d_in[16];
    const float* bo2 = (const float*)d_in[17];
    const float* Wo3 = (const float*)d_in[18];
    const float* bo3 = (const float*)d_in[19];

    const int NV = in_sizes[0];
    const int NC = in_sizes[2];
    const int E  = in_sizes[3];

    // ---- fast-path layout: ebufS and ebufD now COEXIST (S-sorted buffer is
    // needed through the end); D-phase chunked so ebufD fits. ----
    auto layout_bytes = [&](int nDc, size_t* offs_out) -> size_t {
        size_t off = 0;
        auto alloc = [&](size_t bytes, int slot) {
            if (offs_out) offs_out[slot] = off;
            off = (off + bytes + 255) & ~(size_t)255;
        };
        size_t EcMax = ((size_t)E + nDc - 1) / nDc;
        alloc((size_t)NC * BST * 4, 0);       // bufC
        alloc((size_t)NV * 16, 1);            // vcx (float4)
        alloc((size_t)NC * 4, 2);             // deg_c
        alloc((size_t)SLC * NBINS * 4, 3);    // hS / offsS
        alloc((size_t)SLC * NBINS * 4, 4);    // hD / offsD (reused per chunk)
        alloc((size_t)NBINS * 4, 5);          // colT
        alloc((size_t)(NBINS + 1) * 4, 6);    // startS
        alloc((size_t)(NBINS + 1) * 4, 7);    // startD
        alloc(8, 8);                          // gacc
        alloc((size_t)E * 8, 9);              // ebufS (persists)
        alloc(EcMax * 16, 10);                // ebufD (per chunk)
        return off;
    };

    int nD = 0;
    size_t offs[11];
    for (int cand = 2; cand <= 16; cand++) {
        if (layout_bytes(cand, nullptr) <= ws_size) { nD = cand; break; }
    }
    bool fast = (nD > 0) && (NV <= (1 << 20)) && (NC <= (1 << 19)) && (E > 0);

    char* ws = (char*)d_ws;
    if (fast) {
        layout_bytes(nD, offs);
        float*    bufC   = (float*)(ws + offs[0]);
        float4*   vcx    = (float4*)(ws + offs[1]);
        float*    deg_c  = (float*)(ws + offs[2]);
        unsigned* hS     = (unsigned*)(ws + offs[3]);
        unsigned* hD     = (unsigned*)(ws + offs[4]);
        unsigned* colT   = (unsigned*)(ws + offs[5]);
        unsigned* startS = (unsigned*)(ws + offs[6]);
        unsigned* startD = (unsigned*)(ws + offs[7]);
        double*   gacc   = (double*)(ws + offs[8]);
        uint2*    ebufS  = (uint2*)(ws + offs[9]);
        uint4*    ebufD  = (uint4*)(ws + offs[10]);

        const long long EcMax = ((long long)E + nD - 1) / nD;
        const int perS = (int)(((long long)E + SLC - 1) / SLC);
        const int perD = (int)((EcMax + SLC - 1) / SLC);
        const int NB_S = (NV + 255) >> 8;
        const int NB_C = (NC + 255) >> 8;

        hipMemsetAsync(bufC,  0, (size_t)NC * BST * 4, stream);
        hipMemsetAsync(deg_c, 0, (size_t)NC * 4, stream);
        hipMemsetAsync(gacc,  0, 8, stream);

        // 1) S-sort (cursors stay valid; ebufS persists to the end)
        k_hist<<<SLC, 1024, 0, stream>>>(src, hS, 0, E, perS);
        k_coltot<<<NBINS / 256, 256, 0, stream>>>(hS, colT);
        k_prefix<<<1, 1024, 0, stream>>>(colT, startS);
        k_offs<<<NBINS / 256, 256, 0, stream>>>(hS, startS);
        k_scatS<<<SLC, 1024, 0, stream>>>(src, dst, A, hS, ebufS, E, perS);

        // 2) degrees from sorted keys -> vcx
        k_cntS2<<<NB_S, 256, 0, stream>>>(ebufS, startS, var_c, var_x, vcx, NV);

        // 3) D chunks: hist -> cursors -> 16-B scatter -> streaming aggregate
        for (int c = 0; c < nD; c++) {
            long long cb = (long long)c * EcMax;
            long long ce = cb + EcMax; if (ce > E) ce = E;
            k_hist<<<SLC, 1024, 0, stream>>>(dst, hD, cb, ce, perD);
            k_coltot<<<NBINS / 256, 256, 0, stream>>>(hD, colT);
            k_prefix<<<1, 1024, 0, stream>>>(colT, startD);
            k_offs<<<NBINS / 256, 256, 0, stream>>>(hD, startD);
            k_scatD<<<SLC, 1024, 0, stream>>>(src, dst, A, hD, vcx, ebufD, cb, ce, perD);
            k_aggD<<<NB_C, 256, 0, stream>>>(ebufD, startD, Wv, bv, bufC, deg_c, NC);
        }
        k_conT<<<NB_C, 256, 0, stream>>>(bufC, deg_c, W2, b2, NC);

        // 4) fused c2v aggregate (cooperative gather) + MLP + mean
        k_aggS<<<NB_S, 256, 0, stream>>>(ebufS, startS, bufC, vcx, W2, b2,
                                         Wo1, bo1, Wo2, bo2, Wo3, bo3, gacc, NV);
        k_out<<<1, 1, 0, stream>>>(gacc, (float*)d_out, NV);
    } else {
        // round-1 fallback
        const int B = 256;
        float* fbufV = (float*)ws;
        float* fbufC = (float*)(ws + (size_t)NV * ST * 4);
        float* deg_v = (float*)(ws + (size_t)(NV + NC) * ST * 4);
        float* deg_c = deg_v + NV;
        size_t acc_off = ((size_t)(NV + NC) * ST * 4 + (size_t)(NV + NC) * 4 + 7) & ~(size_t)7;
        double* acc = (double*)(ws + acc_off);

        hipMemsetAsync(deg_v, 0, (size_t)(NV + NC) * 4, stream);
        hipMemsetAsync(fbufC, 0, (size_t)NC * ST * 4, stream);
        hipMemsetAsync(acc, 0, sizeof(double), stream);

        k_degree<<<(E + B - 1) / B, B, 0, stream>>>(src, dst, deg_v, deg_c, E);
        k_norm<<<(NV + NC + B - 1) / B, B, 0, stream>>>(deg_v, NV + NC);
        k_var_emb<<<(NV + B - 1) / B, B, 0, stream>>>(var_c, var_x, deg_v, Wv, bv, W2, fbufV, NV);

        long long tE = (long long)E * 5;
        k_edge<<<(int)((tE + B - 1) / B), B, 0, stream>>>(src, dst, A, fbufV, fbufC, E);
        k_con<<<(NC + B - 1) / B, B, 0, stream>>>(fbufC, deg_c, W2, b2, NC);

        hipMemsetAsync(fbufV, 0, (size_t)NV * ST * 4, stream);
        k_edge<<<(int)((tE + B - 1) / B), B, 0, stream>>>(dst, src, A, fbufC, fbufV, E);

        k_final<<<(NV + B - 1) / B, B, 0, stream>>>(fbufV, deg_v, b2, Wo1, bo1, Wo2, bo2, Wo3, bo3, acc, NV);
        k_out<<<1, 1, 0, stream>>>(acc, (float*)d_out, NV);
    }
}